// Round 1
// baseline (3969.473 us; speedup 1.0000x reference)
//
#include <hip/hip_runtime.h>
#include <math.h>

#define KNOW 128
#define STU_N 50000
#define EXER_N 20000
#define BATCH 8192
#define NE 1000000
#define NEP 950000
#define SOFT_INV 5.0f   // 1/0.2
#define EPS 1e-8f

// ---------------- scatter: A[dst] += exer[src], deg[dst] += 1 ----------------
// 32 threads per edge, each handles a float4 chunk of the 128-wide row.
__global__ __launch_bounds__(256) void scatter_edges(
    const float* __restrict__ exer, const int* __restrict__ src,
    const int* __restrict__ dst, float* __restrict__ A,
    float* __restrict__ deg, int nedges) {
  long long tid = (long long)blockIdx.x * blockDim.x + threadIdx.x;
  int e = (int)(tid >> 5);
  int c = (int)(tid & 31);
  if (e >= nedges) return;
  int s = src[e];
  int d = dst[e];
  const float4 v = *(const float4*)(exer + (size_t)s * KNOW + c * 4);
  float* out = A + (size_t)d * KNOW + c * 4;
  atomicAdd(out + 0, v.x);
  atomicAdd(out + 1, v.y);
  atomicAdd(out + 2, v.z);
  atomicAdd(out + 3, v.w);
  if (c == 0) atomicAdd(deg + d, 1.0f);
}

// ---------------- W_sum = W_ue + W_deep ----------------
__global__ void wsum_kernel(const float* __restrict__ Wa,
                            const float* __restrict__ Wb,
                            float* __restrict__ Ws) {
  int t = blockIdx.x * blockDim.x + threadIdx.x;
  if (t < KNOW * KNOW) Ws[t] = Wa[t] + Wb[t];
}

// ---------------- stu2 = stu_emb + (A_e/deg_e) @ W_sum ----------------
#define SPB 16
__global__ __launch_bounds__(128) void stu2_kernel(
    const float* __restrict__ stu_emb, const float* __restrict__ A_e,
    const float* __restrict__ deg_e, const float* __restrict__ Ws,
    float* __restrict__ out) {
  __shared__ float w[KNOW * KNOW];   // 64 KB
  __shared__ float a[SPB * KNOW];    // 8 KB
  int k = threadIdx.x;
  int s0 = blockIdx.x * SPB;
  for (int j = 0; j < KNOW; ++j) w[j * KNOW + k] = Ws[j * KNOW + k];
  for (int si = 0; si < SPB; ++si) {
    int s = s0 + si;
    if (s < STU_N) {
      float dg = fmaxf(deg_e[s], 1.0f);
      a[si * KNOW + k] = A_e[(size_t)s * KNOW + k] / dg;
    } else {
      a[si * KNOW + k] = 0.0f;
    }
  }
  __syncthreads();
  for (int si = 0; si < SPB; ++si) {
    int s = s0 + si;
    if (s >= STU_N) break;
    float acc = 0.0f;
#pragma unroll
    for (int j = 0; j < KNOW; ++j) acc += a[si * KNOW + j] * w[j * KNOW + k];
    out[(size_t)s * KNOW + k] = stu_emb[(size_t)s * KNOW + k] + acc;
  }
}

// ---------------- batch: gather b1, compute b2, normalize, S2 += n2 ----------------
__global__ __launch_bounds__(128) void batch_kernel(
    const float* __restrict__ stu_emb, const float* __restrict__ stu2,
    const float* __restrict__ A_e, const float* __restrict__ deg_e,
    const float* __restrict__ A_p, const float* __restrict__ deg_p,
    const float* __restrict__ W_per, const float* __restrict__ W_deep,
    const int* __restrict__ stu_id, float* __restrict__ n1,
    float* __restrict__ n2, float* __restrict__ S2) {
  __shared__ float ae[KNOW], ap[KNOW];
  __shared__ float red[128];
  int i = blockIdx.x;
  int k = threadIdx.x;
  int sid = stu_id[i];
  float de = fmaxf(deg_e[sid], 1.0f);
  float dp = fmaxf(deg_p[sid], 1.0f);
  ae[k] = A_e[(size_t)sid * KNOW + k] / de;
  ap[k] = A_p[(size_t)sid * KNOW + k] / dp;
  __syncthreads();
  float b1 = stu2[(size_t)sid * KNOW + k];
  float b2 = stu_emb[(size_t)sid * KNOW + k];
#pragma unroll 4
  for (int j = 0; j < KNOW; ++j)
    b2 += ap[j] * W_per[j * KNOW + k] + ae[j] * W_deep[j * KNOW + k];

  red[k] = b1 * b1;
  __syncthreads();
  for (int s = 64; s > 0; s >>= 1) {
    if (k < s) red[k] += red[k + s];
    __syncthreads();
  }
  float norm1 = sqrtf(red[0]);
  __syncthreads();
  red[k] = b2 * b2;
  __syncthreads();
  for (int s = 64; s > 0; s >>= 1) {
    if (k < s) red[k] += red[k + s];
    __syncthreads();
  }
  float norm2 = sqrtf(red[0]);

  float v1 = b1 / norm1;
  float v2 = b2 / norm2;
  n1[(size_t)i * KNOW + k] = v1;
  n2[(size_t)i * KNOW + k] = v2;
  atomicAdd(&S2[k], v2);
}

// ---------------- loss: per row, diag & row_sum dots ----------------
__global__ __launch_bounds__(128) void loss_kernel(
    const float* __restrict__ n1, const float* __restrict__ n2,
    const float* __restrict__ S2, float* __restrict__ loss) {
  __shared__ float r1[128], r2[128];
  int i = blockIdx.x;
  int k = threadIdx.x;
  float a = n1[(size_t)i * KNOW + k];
  r1[k] = a * n2[(size_t)i * KNOW + k];
  r2[k] = a * S2[k];
  __syncthreads();
  for (int s = 64; s > 0; s >>= 1) {
    if (k < s) { r1[k] += r1[k + s]; r2[k] += r2[k + s]; }
    __syncthreads();
  }
  if (k == 0) {
    float diag = r1[0] * SOFT_INV;
    float rs = r2[0] * SOFT_INV;
    float ratio = expf(diag) / (rs + EPS);
    float li = -logf(fmaxf(ratio, EPS));
    atomicAdd(loss, li);
  }
}

__global__ void finalize_kernel(const float* __restrict__ loss,
                                float* __restrict__ out) {
  out[(size_t)STU_N * KNOW] = loss[0] * (1.0f / (float)BATCH);
}

extern "C" void kernel_launch(void* const* d_in, const int* in_sizes, int n_in,
                              void* d_out, int out_size, void* d_ws,
                              size_t ws_size, hipStream_t stream) {
  const float* stu_emb = (const float*)d_in[0];
  const float* exer_emb = (const float*)d_in[1];
  const float* W_ue = (const float*)d_in[2];
  const float* W_ue_per = (const float*)d_in[3];
  const float* W_deep = (const float*)d_in[4];
  const int* src_e = (const int*)d_in[5];
  const int* dst_e = (const int*)d_in[6];
  const int* src_p = (const int*)d_in[7];
  const int* dst_p = (const int*)d_in[8];
  const int* stu_id = (const int*)d_in[9];
  float* out = (float*)d_out;

  // workspace layout (floats)
  float* ws = (float*)d_ws;
  float* A_e = ws;                          // 6,400,000
  float* A_p = A_e + (size_t)STU_N * KNOW;  // 6,400,000
  float* deg_e = A_p + (size_t)STU_N * KNOW;  // 50,000
  float* deg_p = deg_e + STU_N;               // 50,000
  float* S2 = deg_p + STU_N;                  // 128
  float* loss = S2 + KNOW;                    // 1
  size_t zero_floats = (size_t)(loss + 1 - ws);
  float* W_sum = loss + 1;                    // 16,384
  float* n1 = W_sum + KNOW * KNOW;            // 1,048,576
  float* n2 = n1 + (size_t)BATCH * KNOW;      // 1,048,576

  hipMemsetAsync(d_ws, 0, zero_floats * sizeof(float), stream);

  wsum_kernel<<<(KNOW * KNOW + 255) / 256, 256, 0, stream>>>(W_ue, W_deep, W_sum);

  {
    long long thr = (long long)NE * 32;
    scatter_edges<<<(unsigned)((thr + 255) / 256), 256, 0, stream>>>(
        exer_emb, src_e, dst_e, A_e, deg_e, NE);
  }
  {
    long long thr = (long long)NEP * 32;
    scatter_edges<<<(unsigned)((thr + 255) / 256), 256, 0, stream>>>(
        exer_emb, src_p, dst_p, A_p, deg_p, NEP);
  }

  stu2_kernel<<<(STU_N + SPB - 1) / SPB, 128, 0, stream>>>(
      stu_emb, A_e, deg_e, W_sum, out);

  batch_kernel<<<BATCH, 128, 0, stream>>>(stu_emb, out, A_e, deg_e, A_p, deg_p,
                                          W_ue_per, W_deep, stu_id, n1, n2, S2);

  loss_kernel<<<BATCH, 128, 0, stream>>>(n1, n2, S2, loss);

  finalize_kernel<<<1, 1, 0, stream>>>(loss, out);
}

// Round 2
// 1014.482 us; speedup vs baseline: 3.9128x; 3.9128x over previous
//
#include <hip/hip_runtime.h>
#include <math.h>

#define KNOW 128
#define STU_N 50000
#define EXER_N 20000
#define BATCH 8192
#define NE 1000000
#define NEP 950000
#define SOFT_INV 5.0f   // 1/0.2
#define EPS 1e-8f

// ---------------- CSR build: count ----------------
__global__ void count_kernel(const int* __restrict__ dst, int* __restrict__ cnt,
                             int n) {
  int e = blockIdx.x * blockDim.x + threadIdx.x;
  if (e < n) atomicAdd(&cnt[dst[e]], 1);
}

// ---------------- CSR build: exclusive scan (single block, 1024 thr) --------
__global__ __launch_bounds__(1024) void scan_kernel(const int* __restrict__ cnt,
                                                    int* __restrict__ off,
                                                    int n) {
  __shared__ int part[1024];
  int t = threadIdx.x;
  int per = (n + 1023) >> 10;
  int base = t * per;
  int end = base + per;
  if (end > n) end = n;
  int s = 0;
  for (int i = base; i < end; ++i) s += cnt[i];
  part[t] = s;
  __syncthreads();
  for (int d = 1; d < 1024; d <<= 1) {
    int v = (t >= d) ? part[t - d] : 0;
    __syncthreads();
    part[t] += v;
    __syncthreads();
  }
  int run = part[t] - s;  // exclusive prefix of this thread's chunk
  for (int i = base; i < end; ++i) {
    off[i] = run;
    run += cnt[i];
  }
  if (t == 1023) off[n] = part[1023];
}

// ---------------- CSR build: fill ----------------
__global__ void fill_kernel(const int* __restrict__ src,
                            const int* __restrict__ dst,
                            const int* __restrict__ off, int* __restrict__ cur,
                            int* __restrict__ csr, int n) {
  int e = blockIdx.x * blockDim.x + threadIdx.x;
  if (e >= n) return;
  int d = dst[e];
  int p = atomicAdd(&cur[d], 1);
  csr[off[d] + p] = src[e];
}

// ---------------- gather mean: A[s] = mean of exer rows over CSR row s ------
__global__ __launch_bounds__(128) void gather_mean(
    const float* __restrict__ exer, const int* __restrict__ csr,
    const int* __restrict__ off, float* __restrict__ A, int nstu) {
  int s = blockIdx.x;
  if (s >= nstu) return;
  int k = threadIdx.x;
  int b = off[s], e = off[s + 1];
  float acc = 0.0f;
  int i = b;
  for (; i + 4 <= e; i += 4) {
    int s0 = csr[i], s1 = csr[i + 1], s2 = csr[i + 2], s3 = csr[i + 3];
    acc += exer[(size_t)s0 * KNOW + k];
    acc += exer[(size_t)s1 * KNOW + k];
    acc += exer[(size_t)s2 * KNOW + k];
    acc += exer[(size_t)s3 * KNOW + k];
  }
  for (; i < e; ++i) acc += exer[(size_t)csr[i] * KNOW + k];
  float inv = 1.0f / fmaxf((float)(e - b), 1.0f);
  A[(size_t)s * KNOW + k] = acc * inv;
}

// ---------------- W_sum = W_ue + W_deep ----------------
__global__ void wsum_kernel(const float* __restrict__ Wa,
                            const float* __restrict__ Wb,
                            float* __restrict__ Ws) {
  int t = blockIdx.x * blockDim.x + threadIdx.x;
  if (t < KNOW * KNOW) Ws[t] = Wa[t] + Wb[t];
}

// ---------------- stu2 = stu_emb + M_e @ W_sum  (M_e already the mean) ------
#define SPB 16
__global__ __launch_bounds__(128) void stu2_kernel(
    const float* __restrict__ stu_emb, const float* __restrict__ M_e,
    const float* __restrict__ Ws, float* __restrict__ out) {
  __shared__ float w[KNOW * KNOW];  // 64 KB
  __shared__ float a[SPB * KNOW];   // 8 KB
  int k = threadIdx.x;
  int s0 = blockIdx.x * SPB;
  for (int j = 0; j < KNOW; ++j) w[j * KNOW + k] = Ws[j * KNOW + k];
  for (int si = 0; si < SPB; ++si) {
    int s = s0 + si;
    a[si * KNOW + k] = (s < STU_N) ? M_e[(size_t)s * KNOW + k] : 0.0f;
  }
  __syncthreads();
  for (int si = 0; si < SPB; ++si) {
    int s = s0 + si;
    if (s >= STU_N) break;
    float acc = 0.0f;
#pragma unroll
    for (int j = 0; j < KNOW; ++j) acc += a[si * KNOW + j] * w[j * KNOW + k];
    out[(size_t)s * KNOW + k] = stu_emb[(size_t)s * KNOW + k] + acc;
  }
}

// ---------------- batch: b1 gather, b2 on-the-fly, normalize, S2 += n2 ------
__global__ __launch_bounds__(128) void batch_kernel(
    const float* __restrict__ stu_emb, const float* __restrict__ stu2,
    const float* __restrict__ M_e, const float* __restrict__ exer,
    const int* __restrict__ csr_p, const int* __restrict__ off_p,
    const float* __restrict__ W_per, const float* __restrict__ W_deep,
    const int* __restrict__ stu_id, float* __restrict__ n1,
    float* __restrict__ n2, float* __restrict__ S2) {
  __shared__ float ae[KNOW], ap[KNOW];
  __shared__ float red[128];
  int i = blockIdx.x;
  int k = threadIdx.x;
  int sid = stu_id[i];

  // per-view aggregate on the fly from CSR_p
  int b = off_p[sid], e = off_p[sid + 1];
  float acc = 0.0f;
  int j = b;
  for (; j + 4 <= e; j += 4) {
    int s0 = csr_p[j], s1 = csr_p[j + 1], s2 = csr_p[j + 2], s3 = csr_p[j + 3];
    acc += exer[(size_t)s0 * KNOW + k];
    acc += exer[(size_t)s1 * KNOW + k];
    acc += exer[(size_t)s2 * KNOW + k];
    acc += exer[(size_t)s3 * KNOW + k];
  }
  for (; j < e; ++j) acc += exer[(size_t)csr_p[j] * KNOW + k];
  ap[k] = acc / fmaxf((float)(e - b), 1.0f);
  ae[k] = M_e[(size_t)sid * KNOW + k];
  __syncthreads();

  float b1 = stu2[(size_t)sid * KNOW + k];
  float b2 = stu_emb[(size_t)sid * KNOW + k];
#pragma unroll 4
  for (int q = 0; q < KNOW; ++q)
    b2 += ap[q] * W_per[q * KNOW + k] + ae[q] * W_deep[q * KNOW + k];

  red[k] = b1 * b1;
  __syncthreads();
  for (int s = 64; s > 0; s >>= 1) {
    if (k < s) red[k] += red[k + s];
    __syncthreads();
  }
  float norm1 = sqrtf(red[0]);
  __syncthreads();
  red[k] = b2 * b2;
  __syncthreads();
  for (int s = 64; s > 0; s >>= 1) {
    if (k < s) red[k] += red[k + s];
    __syncthreads();
  }
  float norm2 = sqrtf(red[0]);

  float v1 = b1 / norm1;
  float v2 = b2 / norm2;
  n1[(size_t)i * KNOW + k] = v1;
  n2[(size_t)i * KNOW + k] = v2;
  atomicAdd(&S2[k], v2);
}

// ---------------- loss ----------------
__global__ __launch_bounds__(128) void loss_kernel(
    const float* __restrict__ n1, const float* __restrict__ n2,
    const float* __restrict__ S2, float* __restrict__ loss) {
  __shared__ float r1[128], r2[128];
  int i = blockIdx.x;
  int k = threadIdx.x;
  float a = n1[(size_t)i * KNOW + k];
  r1[k] = a * n2[(size_t)i * KNOW + k];
  r2[k] = a * S2[k];
  __syncthreads();
  for (int s = 64; s > 0; s >>= 1) {
    if (k < s) {
      r1[k] += r1[k + s];
      r2[k] += r2[k + s];
    }
    __syncthreads();
  }
  if (k == 0) {
    float diag = r1[0] * SOFT_INV;
    float rs = r2[0] * SOFT_INV;
    float ratio = expf(diag) / (rs + EPS);
    float li = -logf(fmaxf(ratio, EPS));
    atomicAdd(loss, li);
  }
}

__global__ void finalize_kernel(const float* __restrict__ loss,
                                float* __restrict__ out) {
  out[(size_t)STU_N * KNOW] = loss[0] * (1.0f / (float)BATCH);
}

extern "C" void kernel_launch(void* const* d_in, const int* in_sizes, int n_in,
                              void* d_out, int out_size, void* d_ws,
                              size_t ws_size, hipStream_t stream) {
  const float* stu_emb = (const float*)d_in[0];
  const float* exer_emb = (const float*)d_in[1];
  const float* W_ue = (const float*)d_in[2];
  const float* W_ue_per = (const float*)d_in[3];
  const float* W_deep = (const float*)d_in[4];
  const int* src_e = (const int*)d_in[5];
  const int* dst_e = (const int*)d_in[6];
  const int* src_p = (const int*)d_in[7];
  const int* dst_p = (const int*)d_in[8];
  const int* stu_id = (const int*)d_in[9];
  float* out = (float*)d_out;

  // ---- workspace layout (4-byte units) ----
  char* wsb = (char*)d_ws;
  // zeroed region first
  int* cnt_e = (int*)wsb;                  // 50,000
  int* cnt_p = cnt_e + STU_N;              // 50,000
  int* cur_e = cnt_p + STU_N;              // 50,000
  int* cur_p = cur_e + STU_N;              // 50,000
  float* S2 = (float*)(cur_p + STU_N);     // 128
  float* loss = S2 + KNOW;                 // 1
  size_t zero_units = (size_t)((int*)(loss + 1) - cnt_e);
  // rest (fully overwritten each call)
  float* M_e = loss + 1;                        // 6,400,000
  int* off_e = (int*)(M_e + (size_t)STU_N * KNOW);  // 50,001
  int* off_p = off_e + STU_N + 1;               // 50,001
  int* csr_e = off_p + STU_N + 1;               // 1,000,000
  int* csr_p = csr_e + NE;                      // 950,000
  float* W_sum = (float*)(csr_p + NEP);         // 16,384
  float* n1 = W_sum + KNOW * KNOW;              // 1,048,576
  float* n2 = n1 + (size_t)BATCH * KNOW;        // 1,048,576

  hipMemsetAsync(d_ws, 0, zero_units * 4, stream);

  wsum_kernel<<<(KNOW * KNOW + 255) / 256, 256, 0, stream>>>(W_ue, W_deep,
                                                             W_sum);

  // CSR build for both edge sets
  count_kernel<<<(NE + 255) / 256, 256, 0, stream>>>(dst_e, cnt_e, NE);
  count_kernel<<<(NEP + 255) / 256, 256, 0, stream>>>(dst_p, cnt_p, NEP);
  scan_kernel<<<1, 1024, 0, stream>>>(cnt_e, off_e, STU_N);
  scan_kernel<<<1, 1024, 0, stream>>>(cnt_p, off_p, STU_N);
  fill_kernel<<<(NE + 255) / 256, 256, 0, stream>>>(src_e, dst_e, off_e, cur_e,
                                                    csr_e, NE);
  fill_kernel<<<(NEP + 255) / 256, 256, 0, stream>>>(src_p, dst_p, off_p,
                                                     cur_p, csr_p, NEP);

  // mean aggregate for the e-view (needed for all students)
  gather_mean<<<STU_N, 128, 0, stream>>>(exer_emb, csr_e, off_e, M_e, STU_N);

  // stu2 = stu_emb + M_e @ (W_ue + W_deep)
  stu2_kernel<<<(STU_N + SPB - 1) / SPB, 128, 0, stream>>>(stu_emb, M_e, W_sum,
                                                           out);

  // batch path (per-view aggregate computed on the fly for sampled rows)
  batch_kernel<<<BATCH, 128, 0, stream>>>(stu_emb, out, M_e, exer_emb, csr_p,
                                          off_p, W_ue_per, W_deep, stu_id, n1,
                                          n2, S2);

  loss_kernel<<<BATCH, 128, 0, stream>>>(n1, n2, S2, loss);

  finalize_kernel<<<1, 1, 0, stream>>>(loss, out);
}

// Round 3
// 940.043 us; speedup vs baseline: 4.2227x; 1.0792x over previous
//
#include <hip/hip_runtime.h>
#include <math.h>

#define KNOW 128
#define STU_N 50000
#define EXER_N 20000
#define BATCH 8192
#define NE 1000000
#define NEP 950000
#define SOFT_INV 5.0f   // 1/0.2
#define EPS 1e-8f

// ---------------- CSR build: count (both edge sets in one launch) -----------
__global__ void count_both(const int* __restrict__ dst_e,
                           const int* __restrict__ dst_p,
                           int* __restrict__ cnt_e, int* __restrict__ cnt_p) {
  int t = blockIdx.x * blockDim.x + threadIdx.x;
  if (t < NE) {
    atomicAdd(&cnt_e[dst_e[t]], 1);
  } else if (t < NE + NEP) {
    atomicAdd(&cnt_p[dst_p[t - NE]], 1);
  }
}

// ---------------- CSR build: exclusive scan (block 0: e, block 1: p) --------
__global__ __launch_bounds__(1024) void scan_both(const int* __restrict__ cnt_e,
                                                  const int* __restrict__ cnt_p,
                                                  int* __restrict__ off_e,
                                                  int* __restrict__ off_p) {
  __shared__ int part[1024];
  const int* cnt = (blockIdx.x == 0) ? cnt_e : cnt_p;
  int* off = (blockIdx.x == 0) ? off_e : off_p;
  const int n = STU_N;
  int t = threadIdx.x;
  int per = (n + 1023) >> 10;
  int base = t * per;
  int end = base + per;
  if (end > n) end = n;
  int s = 0;
  for (int i = base; i < end; ++i) s += cnt[i];
  part[t] = s;
  __syncthreads();
  for (int d = 1; d < 1024; d <<= 1) {
    int v = (t >= d) ? part[t - d] : 0;
    __syncthreads();
    part[t] += v;
    __syncthreads();
  }
  int run = part[t] - s;
  for (int i = base; i < end; ++i) {
    off[i] = run;
    run += cnt[i];
  }
  if (t == 1023) off[n] = part[1023];
}

// ---------------- CSR build: fill (both edge sets in one launch) ------------
__global__ void fill_both(const int* __restrict__ src_e,
                          const int* __restrict__ dst_e,
                          const int* __restrict__ src_p,
                          const int* __restrict__ dst_p,
                          const int* __restrict__ off_e,
                          const int* __restrict__ off_p,
                          int* __restrict__ cur_e, int* __restrict__ cur_p,
                          int* __restrict__ csr_e, int* __restrict__ csr_p) {
  int t = blockIdx.x * blockDim.x + threadIdx.x;
  if (t < NE) {
    int d = dst_e[t];
    int p = atomicAdd(&cur_e[d], 1);
    csr_e[off_e[d] + p] = src_e[t];
  } else if (t < NE + NEP) {
    int e = t - NE;
    int d = dst_p[e];
    int p = atomicAdd(&cur_p[d], 1);
    csr_p[off_p[d] + p] = src_p[e];
  }
}

// ---------------- X_sum/X_per/X_deep = exer @ {W_ue+W_deep, W_per, W_deep} --
#define TRO 16  // exer rows per block
__global__ __launch_bounds__(128) void transform_kernel(
    const float* __restrict__ exer, const float* __restrict__ W_ue,
    const float* __restrict__ W_per, const float* __restrict__ W_deep,
    float* __restrict__ X_sum, float* __restrict__ X_per,
    float* __restrict__ X_deep) {
  __shared__ float w[KNOW * KNOW];  // 64 KB
  __shared__ float a[TRO * KNOW];   // 8 KB
  int k = threadIdx.x;
  int which = blockIdx.y;
  const float* Wsrc = (which == 0) ? W_ue : (which == 1) ? W_per : W_deep;
  float* outp = (which == 0) ? X_sum : (which == 1) ? X_per : X_deep;
  if (which == 0) {
    for (int j = 0; j < KNOW; ++j)
      w[j * KNOW + k] = Wsrc[j * KNOW + k] + W_deep[j * KNOW + k];
  } else {
    for (int j = 0; j < KNOW; ++j) w[j * KNOW + k] = Wsrc[j * KNOW + k];
  }
  int r0 = blockIdx.x * TRO;
  for (int ri = 0; ri < TRO; ++ri) {
    int r = r0 + ri;
    a[ri * KNOW + k] = (r < EXER_N) ? exer[(size_t)r * KNOW + k] : 0.0f;
  }
  __syncthreads();
  for (int ri = 0; ri < TRO; ++ri) {
    int r = r0 + ri;
    if (r >= EXER_N) break;
    float acc = 0.0f;
#pragma unroll
    for (int j = 0; j < KNOW; ++j) acc += a[ri * KNOW + j] * w[j * KNOW + k];
    outp[(size_t)r * KNOW + k] = acc;
  }
}

// ---------------- stu2 = stu_emb + mean(X_sum rows over CSR_e) --------------
__global__ __launch_bounds__(128) void stu2_gather(
    const float* __restrict__ stu_emb, const float* __restrict__ X_sum,
    const int* __restrict__ csr, const int* __restrict__ off,
    float* __restrict__ out) {
  int s = blockIdx.x;
  int k = threadIdx.x;
  int b = off[s], e = off[s + 1];
  float acc = 0.0f;
  int i = b;
  for (; i + 4 <= e; i += 4) {
    int s0 = csr[i], s1 = csr[i + 1], s2 = csr[i + 2], s3 = csr[i + 3];
    acc += X_sum[(size_t)s0 * KNOW + k];
    acc += X_sum[(size_t)s1 * KNOW + k];
    acc += X_sum[(size_t)s2 * KNOW + k];
    acc += X_sum[(size_t)s3 * KNOW + k];
  }
  for (; i < e; ++i) acc += X_sum[(size_t)csr[i] * KNOW + k];
  float inv = 1.0f / fmaxf((float)(e - b), 1.0f);
  out[(size_t)s * KNOW + k] = stu_emb[(size_t)s * KNOW + k] + acc * inv;
}

// ---------------- batch: pure gathers, normalize, S2 += n2 ------------------
__global__ __launch_bounds__(128) void batch_kernel(
    const float* __restrict__ stu_emb, const float* __restrict__ stu2,
    const float* __restrict__ X_per, const float* __restrict__ X_deep,
    const int* __restrict__ csr_p, const int* __restrict__ off_p,
    const int* __restrict__ csr_e, const int* __restrict__ off_e,
    const int* __restrict__ stu_id, float* __restrict__ n1,
    float* __restrict__ n2, float* __restrict__ S2) {
  __shared__ float red[128];
  int i = blockIdx.x;
  int k = threadIdx.x;
  int sid = stu_id[i];

  // mean(X_per[csr_p row sid])
  int b = off_p[sid], e = off_p[sid + 1];
  float accp = 0.0f;
  int j = b;
  for (; j + 4 <= e; j += 4) {
    int s0 = csr_p[j], s1 = csr_p[j + 1], s2 = csr_p[j + 2], s3 = csr_p[j + 3];
    accp += X_per[(size_t)s0 * KNOW + k];
    accp += X_per[(size_t)s1 * KNOW + k];
    accp += X_per[(size_t)s2 * KNOW + k];
    accp += X_per[(size_t)s3 * KNOW + k];
  }
  for (; j < e; ++j) accp += X_per[(size_t)csr_p[j] * KNOW + k];
  accp /= fmaxf((float)(e - b), 1.0f);

  // mean(X_deep[csr_e row sid])
  int b2i = off_e[sid], e2i = off_e[sid + 1];
  float accd = 0.0f;
  j = b2i;
  for (; j + 4 <= e2i; j += 4) {
    int s0 = csr_e[j], s1 = csr_e[j + 1], s2 = csr_e[j + 2], s3 = csr_e[j + 3];
    accd += X_deep[(size_t)s0 * KNOW + k];
    accd += X_deep[(size_t)s1 * KNOW + k];
    accd += X_deep[(size_t)s2 * KNOW + k];
    accd += X_deep[(size_t)s3 * KNOW + k];
  }
  for (; j < e2i; ++j) accd += X_deep[(size_t)csr_e[j] * KNOW + k];
  accd /= fmaxf((float)(e2i - b2i), 1.0f);

  float b1 = stu2[(size_t)sid * KNOW + k];
  float b2 = stu_emb[(size_t)sid * KNOW + k] + accp + accd;

  red[k] = b1 * b1;
  __syncthreads();
  for (int s = 64; s > 0; s >>= 1) {
    if (k < s) red[k] += red[k + s];
    __syncthreads();
  }
  float norm1 = sqrtf(red[0]);
  __syncthreads();
  red[k] = b2 * b2;
  __syncthreads();
  for (int s = 64; s > 0; s >>= 1) {
    if (k < s) red[k] += red[k + s];
    __syncthreads();
  }
  float norm2 = sqrtf(red[0]);

  float v1 = b1 / norm1;
  float v2 = b2 / norm2;
  n1[(size_t)i * KNOW + k] = v1;
  n2[(size_t)i * KNOW + k] = v2;
  atomicAdd(&S2[k], v2);
}

// ---------------- loss ----------------
__global__ __launch_bounds__(128) void loss_kernel(
    const float* __restrict__ n1, const float* __restrict__ n2,
    const float* __restrict__ S2, float* __restrict__ loss) {
  __shared__ float r1[128], r2[128];
  int i = blockIdx.x;
  int k = threadIdx.x;
  float a = n1[(size_t)i * KNOW + k];
  r1[k] = a * n2[(size_t)i * KNOW + k];
  r2[k] = a * S2[k];
  __syncthreads();
  for (int s = 64; s > 0; s >>= 1) {
    if (k < s) {
      r1[k] += r1[k + s];
      r2[k] += r2[k + s];
    }
    __syncthreads();
  }
  if (k == 0) {
    float diag = r1[0] * SOFT_INV;
    float rs = r2[0] * SOFT_INV;
    float ratio = expf(diag) / (rs + EPS);
    float li = -logf(fmaxf(ratio, EPS));
    atomicAdd(loss, li);
  }
}

__global__ void finalize_kernel(const float* __restrict__ loss,
                                float* __restrict__ out) {
  out[(size_t)STU_N * KNOW] = loss[0] * (1.0f / (float)BATCH);
}

extern "C" void kernel_launch(void* const* d_in, const int* in_sizes, int n_in,
                              void* d_out, int out_size, void* d_ws,
                              size_t ws_size, hipStream_t stream) {
  const float* stu_emb = (const float*)d_in[0];
  const float* exer_emb = (const float*)d_in[1];
  const float* W_ue = (const float*)d_in[2];
  const float* W_ue_per = (const float*)d_in[3];
  const float* W_deep = (const float*)d_in[4];
  const int* src_e = (const int*)d_in[5];
  const int* dst_e = (const int*)d_in[6];
  const int* src_p = (const int*)d_in[7];
  const int* dst_p = (const int*)d_in[8];
  const int* stu_id = (const int*)d_in[9];
  float* out = (float*)d_out;

  // ---- workspace layout (4-byte units) ----
  char* wsb = (char*)d_ws;
  // zeroed region first
  int* cnt_e = (int*)wsb;               // 50,000
  int* cnt_p = cnt_e + STU_N;           // 50,000
  int* cur_e = cnt_p + STU_N;           // 50,000
  int* cur_p = cur_e + STU_N;           // 50,000
  float* S2 = (float*)(cur_p + STU_N);  // 128
  float* loss = S2 + KNOW;              // 1
  size_t zero_units = (size_t)((int*)(loss + 1) - cnt_e);
  // rest (fully overwritten each call)
  float* X_sum = loss + 1;                           // 2,560,000
  float* X_per = X_sum + (size_t)EXER_N * KNOW;      // 2,560,000
  float* X_deep = X_per + (size_t)EXER_N * KNOW;     // 2,560,000
  int* off_e = (int*)(X_deep + (size_t)EXER_N * KNOW);  // 50,001
  int* off_p = off_e + STU_N + 1;                    // 50,001
  int* csr_e = off_p + STU_N + 1;                    // 1,000,000
  int* csr_p = csr_e + NE;                           // 950,000
  float* n1 = (float*)(csr_p + NEP);                 // 1,048,576
  float* n2 = n1 + (size_t)BATCH * KNOW;             // 1,048,576

  hipMemsetAsync(d_ws, 0, zero_units * 4, stream);

  // exercise-level transforms (independent of CSR)
  {
    dim3 grid((EXER_N + TRO - 1) / TRO, 3);
    transform_kernel<<<grid, 128, 0, stream>>>(exer_emb, W_ue, W_ue_per,
                                               W_deep, X_sum, X_per, X_deep);
  }

  // CSR build for both edge sets (fused launches)
  count_both<<<(NE + NEP + 255) / 256, 256, 0, stream>>>(dst_e, dst_p, cnt_e,
                                                         cnt_p);
  scan_both<<<2, 1024, 0, stream>>>(cnt_e, cnt_p, off_e, off_p);
  fill_both<<<(NE + NEP + 255) / 256, 256, 0, stream>>>(
      src_e, dst_e, src_p, dst_p, off_e, off_p, cur_e, cur_p, csr_e, csr_p);

  // stu2 = stu_emb + mean(X_sum over CSR_e)
  stu2_gather<<<STU_N, 128, 0, stream>>>(stu_emb, X_sum, csr_e, off_e, out);

  // batch path — pure gathers
  batch_kernel<<<BATCH, 128, 0, stream>>>(stu_emb, out, X_per, X_deep, csr_p,
                                          off_p, csr_e, off_e, stu_id, n1, n2,
                                          S2);

  loss_kernel<<<BATCH, 128, 0, stream>>>(n1, n2, S2, loss);

  finalize_kernel<<<1, 1, 0, stream>>>(loss, out);
}

// Round 4
// 619.217 us; speedup vs baseline: 6.4105x; 1.5181x over previous
//
#include <hip/hip_runtime.h>
#include <math.h>

#define KNOW 128
#define STU_N 50000
#define EXER_N 20000
#define BATCH 8192
#define NE 1000000
#define NEP 950000
#define SOFT_INV 5.0f   // 1/0.2
#define EPS 1e-8f

// ---------------- CSR build: count (both edge sets in one launch) -----------
__global__ void count_both(const int* __restrict__ dst_e,
                           const int* __restrict__ dst_p,
                           int* __restrict__ cnt_e, int* __restrict__ cnt_p) {
  int t = blockIdx.x * blockDim.x + threadIdx.x;
  if (t < NE) {
    atomicAdd(&cnt_e[dst_e[t]], 1);
  } else if (t < NE + NEP) {
    atomicAdd(&cnt_p[dst_p[t - NE]], 1);
  }
}

// ---------------- CSR build: exclusive scan (block 0: e, block 1: p) --------
__global__ __launch_bounds__(1024) void scan_both(const int* __restrict__ cnt_e,
                                                  const int* __restrict__ cnt_p,
                                                  int* __restrict__ off_e,
                                                  int* __restrict__ off_p) {
  __shared__ int part[1024];
  const int* cnt = (blockIdx.x == 0) ? cnt_e : cnt_p;
  int* off = (blockIdx.x == 0) ? off_e : off_p;
  const int n = STU_N;
  int t = threadIdx.x;
  int per = (n + 1023) >> 10;
  int base = t * per;
  int end = base + per;
  if (end > n) end = n;
  int s = 0;
  for (int i = base; i < end; ++i) s += cnt[i];
  part[t] = s;
  __syncthreads();
  for (int d = 1; d < 1024; d <<= 1) {
    int v = (t >= d) ? part[t - d] : 0;
    __syncthreads();
    part[t] += v;
    __syncthreads();
  }
  int run = part[t] - s;
  for (int i = base; i < end; ++i) {
    off[i] = run;
    run += cnt[i];
  }
  if (t == 1023) off[n] = part[1023];
}

// ---------------- CSR build: fill (both edge sets in one launch) ------------
__global__ void fill_both(const int* __restrict__ src_e,
                          const int* __restrict__ dst_e,
                          const int* __restrict__ src_p,
                          const int* __restrict__ dst_p,
                          const int* __restrict__ off_e,
                          const int* __restrict__ off_p,
                          int* __restrict__ cur_e, int* __restrict__ cur_p,
                          int* __restrict__ csr_e, int* __restrict__ csr_p) {
  int t = blockIdx.x * blockDim.x + threadIdx.x;
  if (t < NE) {
    int d = dst_e[t];
    int p = atomicAdd(&cur_e[d], 1);
    csr_e[off_e[d] + p] = src_e[t];
  } else if (t < NE + NEP) {
    int e = t - NE;
    int d = dst_p[e];
    int p = atomicAdd(&cur_p[d], 1);
    csr_p[off_p[d] + p] = src_p[e];
  }
}

// ------- X_sum/X_per/X_deep = exer @ {W_ue+W_deep, W_per, W_deep} -----------
// register-tiled: 256 thr, 32x128 tile/block, 4x4 regs/thread, k unrolled x4
#define TBM 32
__global__ __launch_bounds__(256) void transform_kernel(
    const float* __restrict__ exer, const float* __restrict__ W_ue,
    const float* __restrict__ W_per, const float* __restrict__ W_deep,
    float* __restrict__ X_sum, float* __restrict__ X_per,
    float* __restrict__ X_deep) {
  __shared__ float w[KNOW * KNOW];  // 64 KB
  __shared__ float a[TBM * KNOW];   // 16 KB
  int t = threadIdx.x;
  int which = blockIdx.y;
  float* outp = (which == 0) ? X_sum : (which == 1) ? X_per : X_deep;

  // stage W (vectorized)
  if (which == 0) {
#pragma unroll
    for (int i = t * 4; i < KNOW * KNOW; i += 1024) {
      float4 wa = *(const float4*)(W_ue + i);
      float4 wd = *(const float4*)(W_deep + i);
      float4 o = {wa.x + wd.x, wa.y + wd.y, wa.z + wd.z, wa.w + wd.w};
      *(float4*)(w + i) = o;
    }
  } else {
    const float* Ws = (which == 1) ? W_per : W_deep;
#pragma unroll
    for (int i = t * 4; i < KNOW * KNOW; i += 1024)
      *(float4*)(w + i) = *(const float4*)(Ws + i);
  }
  // stage A rows (20000 = 625*32, no guards needed)
  int r0 = blockIdx.x * TBM;
#pragma unroll
  for (int i = t * 4; i < TBM * KNOW; i += 1024)
    *(float4*)(a + i) = *(const float4*)(exer + (size_t)r0 * KNOW + i);
  __syncthreads();

  int cg = (t & 31) * 4;   // col group (float4)
  int rg = (t >> 5) * 4;   // row group
  float acc[4][4] = {};
  for (int k = 0; k < KNOW; k += 4) {
    float4 wv0 = *(const float4*)(w + (k + 0) * KNOW + cg);
    float4 wv1 = *(const float4*)(w + (k + 1) * KNOW + cg);
    float4 wv2 = *(const float4*)(w + (k + 2) * KNOW + cg);
    float4 wv3 = *(const float4*)(w + (k + 3) * KNOW + cg);
#pragma unroll
    for (int r = 0; r < 4; ++r) {
      float4 av = *(const float4*)(a + (rg + r) * KNOW + k);
      acc[r][0] += av.x * wv0.x + av.y * wv1.x + av.z * wv2.x + av.w * wv3.x;
      acc[r][1] += av.x * wv0.y + av.y * wv1.y + av.z * wv2.y + av.w * wv3.y;
      acc[r][2] += av.x * wv0.z + av.y * wv1.z + av.z * wv2.z + av.w * wv3.z;
      acc[r][3] += av.x * wv0.w + av.y * wv1.w + av.z * wv2.w + av.w * wv3.w;
    }
  }
#pragma unroll
  for (int r = 0; r < 4; ++r) {
    float4 o = {acc[r][0], acc[r][1], acc[r][2], acc[r][3]};
    *(float4*)(outp + (size_t)(r0 + rg + r) * KNOW + cg) = o;
  }
}

// ---------------- stu2 = stu_emb + mean(X_sum rows over CSR_e) --------------
__global__ __launch_bounds__(128) void stu2_gather(
    const float* __restrict__ stu_emb, const float* __restrict__ X_sum,
    const int* __restrict__ csr, const int* __restrict__ off,
    float* __restrict__ out) {
  int s = blockIdx.x;
  int k = threadIdx.x;
  int b = off[s], e = off[s + 1];
  float acc = 0.0f;
  int i = b;
  for (; i + 4 <= e; i += 4) {
    int s0 = csr[i], s1 = csr[i + 1], s2 = csr[i + 2], s3 = csr[i + 3];
    acc += X_sum[(size_t)s0 * KNOW + k];
    acc += X_sum[(size_t)s1 * KNOW + k];
    acc += X_sum[(size_t)s2 * KNOW + k];
    acc += X_sum[(size_t)s3 * KNOW + k];
  }
  for (; i < e; ++i) acc += X_sum[(size_t)csr[i] * KNOW + k];
  float inv = 1.0f / fmaxf((float)(e - b), 1.0f);
  out[(size_t)s * KNOW + k] = stu_emb[(size_t)s * KNOW + k] + acc * inv;
}

// ---------------- batch: pure gathers, normalize, write n1/n2 ---------------
__global__ __launch_bounds__(128) void batch_kernel(
    const float* __restrict__ stu_emb, const float* __restrict__ stu2,
    const float* __restrict__ X_per, const float* __restrict__ X_deep,
    const int* __restrict__ csr_p, const int* __restrict__ off_p,
    const int* __restrict__ csr_e, const int* __restrict__ off_e,
    const int* __restrict__ stu_id, float* __restrict__ n1,
    float* __restrict__ n2) {
  __shared__ float red[128];
  int i = blockIdx.x;
  int k = threadIdx.x;
  int sid = stu_id[i];

  // mean(X_per[csr_p row sid])
  int b = off_p[sid], e = off_p[sid + 1];
  float accp = 0.0f;
  int j = b;
  for (; j + 4 <= e; j += 4) {
    int s0 = csr_p[j], s1 = csr_p[j + 1], s2 = csr_p[j + 2], s3 = csr_p[j + 3];
    accp += X_per[(size_t)s0 * KNOW + k];
    accp += X_per[(size_t)s1 * KNOW + k];
    accp += X_per[(size_t)s2 * KNOW + k];
    accp += X_per[(size_t)s3 * KNOW + k];
  }
  for (; j < e; ++j) accp += X_per[(size_t)csr_p[j] * KNOW + k];
  accp /= fmaxf((float)(e - b), 1.0f);

  // mean(X_deep[csr_e row sid])
  int b2i = off_e[sid], e2i = off_e[sid + 1];
  float accd = 0.0f;
  j = b2i;
  for (; j + 4 <= e2i; j += 4) {
    int s0 = csr_e[j], s1 = csr_e[j + 1], s2 = csr_e[j + 2], s3 = csr_e[j + 3];
    accd += X_deep[(size_t)s0 * KNOW + k];
    accd += X_deep[(size_t)s1 * KNOW + k];
    accd += X_deep[(size_t)s2 * KNOW + k];
    accd += X_deep[(size_t)s3 * KNOW + k];
  }
  for (; j < e2i; ++j) accd += X_deep[(size_t)csr_e[j] * KNOW + k];
  accd /= fmaxf((float)(e2i - b2i), 1.0f);

  float b1 = stu2[(size_t)sid * KNOW + k];
  float b2 = stu_emb[(size_t)sid * KNOW + k] + accp + accd;

  red[k] = b1 * b1;
  __syncthreads();
  for (int s = 64; s > 0; s >>= 1) {
    if (k < s) red[k] += red[k + s];
    __syncthreads();
  }
  float norm1 = sqrtf(red[0]);
  __syncthreads();
  red[k] = b2 * b2;
  __syncthreads();
  for (int s = 64; s > 0; s >>= 1) {
    if (k < s) red[k] += red[k + s];
    __syncthreads();
  }
  float norm2 = sqrtf(red[0]);

  n1[(size_t)i * KNOW + k] = b1 / norm1;
  n2[(size_t)i * KNOW + k] = b2 / norm2;
}

// ---------------- S2[k] = sum_i n2[i][k] (low-contention) -------------------
__global__ __launch_bounds__(128) void s2_reduce(const float* __restrict__ n2,
                                                 float* __restrict__ S2) {
  int k = threadIdx.x;
  int r0 = blockIdx.x * (BATCH / 64);
  float acc = 0.0f;
  for (int r = 0; r < BATCH / 64; ++r)
    acc += n2[(size_t)(r0 + r) * KNOW + k];
  atomicAdd(&S2[k], acc);
}

// ---------------- loss ----------------
__global__ __launch_bounds__(128) void loss_kernel(
    const float* __restrict__ n1, const float* __restrict__ n2,
    const float* __restrict__ S2, float* __restrict__ loss) {
  __shared__ float r1[128], r2[128];
  int i = blockIdx.x;
  int k = threadIdx.x;
  float a = n1[(size_t)i * KNOW + k];
  r1[k] = a * n2[(size_t)i * KNOW + k];
  r2[k] = a * S2[k];
  __syncthreads();
  for (int s = 64; s > 0; s >>= 1) {
    if (k < s) {
      r1[k] += r1[k + s];
      r2[k] += r2[k + s];
    }
    __syncthreads();
  }
  if (k == 0) {
    float diag = r1[0] * SOFT_INV;
    float rs = r2[0] * SOFT_INV;
    float ratio = expf(diag) / (rs + EPS);
    float li = -logf(fmaxf(ratio, EPS));
    atomicAdd(loss, li);
  }
}

__global__ void finalize_kernel(const float* __restrict__ loss,
                                float* __restrict__ out) {
  out[(size_t)STU_N * KNOW] = loss[0] * (1.0f / (float)BATCH);
}

extern "C" void kernel_launch(void* const* d_in, const int* in_sizes, int n_in,
                              void* d_out, int out_size, void* d_ws,
                              size_t ws_size, hipStream_t stream) {
  const float* stu_emb = (const float*)d_in[0];
  const float* exer_emb = (const float*)d_in[1];
  const float* W_ue = (const float*)d_in[2];
  const float* W_ue_per = (const float*)d_in[3];
  const float* W_deep = (const float*)d_in[4];
  const int* src_e = (const int*)d_in[5];
  const int* dst_e = (const int*)d_in[6];
  const int* src_p = (const int*)d_in[7];
  const int* dst_p = (const int*)d_in[8];
  const int* stu_id = (const int*)d_in[9];
  float* out = (float*)d_out;

  // ---- workspace layout (4-byte units) ----
  char* wsb = (char*)d_ws;
  // zeroed region first
  int* cnt_e = (int*)wsb;               // 50,000
  int* cnt_p = cnt_e + STU_N;           // 50,000
  int* cur_e = cnt_p + STU_N;           // 50,000
  int* cur_p = cur_e + STU_N;           // 50,000
  float* S2 = (float*)(cur_p + STU_N);  // 128
  float* loss = S2 + KNOW;              // 1
  size_t zero_units = (size_t)((int*)(loss + 1) - cnt_e);
  // rest (fully overwritten each call)
  float* X_sum = loss + 1;                              // 2,560,000
  float* X_per = X_sum + (size_t)EXER_N * KNOW;         // 2,560,000
  float* X_deep = X_per + (size_t)EXER_N * KNOW;        // 2,560,000
  int* off_e = (int*)(X_deep + (size_t)EXER_N * KNOW);  // 50,001
  int* off_p = off_e + STU_N + 1;                       // 50,001
  int* csr_e = off_p + STU_N + 1;                       // 1,000,000
  int* csr_p = csr_e + NE;                              // 950,000
  float* n1 = (float*)(csr_p + NEP);                    // 1,048,576
  float* n2 = n1 + (size_t)BATCH * KNOW;                // 1,048,576

  hipMemsetAsync(d_ws, 0, zero_units * 4, stream);

  // exercise-level transforms (independent of CSR)
  {
    dim3 grid(EXER_N / TBM, 3);
    transform_kernel<<<grid, 256, 0, stream>>>(exer_emb, W_ue, W_ue_per,
                                               W_deep, X_sum, X_per, X_deep);
  }

  // CSR build for both edge sets (fused launches)
  count_both<<<(NE + NEP + 255) / 256, 256, 0, stream>>>(dst_e, dst_p, cnt_e,
                                                         cnt_p);
  scan_both<<<2, 1024, 0, stream>>>(cnt_e, cnt_p, off_e, off_p);
  fill_both<<<(NE + NEP + 255) / 256, 256, 0, stream>>>(
      src_e, dst_e, src_p, dst_p, off_e, off_p, cur_e, cur_p, csr_e, csr_p);

  // stu2 = stu_emb + mean(X_sum over CSR_e)
  stu2_gather<<<STU_N, 128, 0, stream>>>(stu_emb, X_sum, csr_e, off_e, out);

  // batch path — pure gathers
  batch_kernel<<<BATCH, 128, 0, stream>>>(stu_emb, out, X_per, X_deep, csr_p,
                                          off_p, csr_e, off_e, stu_id, n1, n2);

  s2_reduce<<<64, 128, 0, stream>>>(n2, S2);

  loss_kernel<<<BATCH, 128, 0, stream>>>(n1, n2, S2, loss);

  finalize_kernel<<<1, 1, 0, stream>>>(loss, out);
}

// Round 5
// 547.687 us; speedup vs baseline: 7.2477x; 1.1306x over previous
//
#include <hip/hip_runtime.h>
#include <math.h>

#define KNOW 128
#define STU_N 50000
#define EXER_N 20000
#define BATCH 8192
#define NE 1000000
#define NEP 950000
#define SOFT_INV 5.0f   // 1/0.2
#define EPS 1e-8f

#define NXCD 8
#define STU_PER_XCD (STU_N / NXCD)  // 6250
#define NCHUNK ((NE + NEP + 255) / 256)
#define BGRP 952  // block-groups per XCD for edge kernels

// ---------------- flag sampled students ----------------
__global__ void set_flags(const int* __restrict__ stu_id,
                          unsigned char* __restrict__ flag) {
  int i = blockIdx.x * blockDim.x + threadIdx.x;
  if (i < BATCH) flag[stu_id[i]] = 1;
}

// ---------------- CSR count, XCD-partitioned by dst range -------------------
// p-edges filtered to flagged (sampled) students.
__global__ __launch_bounds__(256) void count_part(
    const int* __restrict__ dst_e, const int* __restrict__ dst_p,
    const unsigned char* __restrict__ flag, int* __restrict__ cnt_e,
    int* __restrict__ cnt_p) {
  int xcd = blockIdx.x & 7;
  int lo = xcd * STU_PER_XCD, hi = lo + STU_PER_XCD;
  for (int c = blockIdx.x >> 3; c < NCHUNK; c += BGRP) {
    int t = (c << 8) + threadIdx.x;
    if (t < NE) {
      int d = dst_e[t];
      if (d >= lo && d < hi) atomicAdd(&cnt_e[d], 1);
    } else if (t < NE + NEP) {
      int d = dst_p[t - NE];
      if (d >= lo && d < hi && flag[d]) atomicAdd(&cnt_p[d], 1);
    }
  }
}

// ---------------- CSR exclusive scan (block 0: e, block 1: p) ---------------
__global__ __launch_bounds__(1024) void scan_both(const int* __restrict__ cnt_e,
                                                  const int* __restrict__ cnt_p,
                                                  int* __restrict__ off_e,
                                                  int* __restrict__ off_p) {
  __shared__ int part[1024];
  const int* cnt = (blockIdx.x == 0) ? cnt_e : cnt_p;
  int* off = (blockIdx.x == 0) ? off_e : off_p;
  const int n = STU_N;
  int t = threadIdx.x;
  int per = (n + 1023) >> 10;
  int base = t * per;
  int end = base + per;
  if (end > n) end = n;
  int s = 0;
  for (int i = base; i < end; ++i) s += cnt[i];
  part[t] = s;
  __syncthreads();
  for (int d = 1; d < 1024; d <<= 1) {
    int v = (t >= d) ? part[t - d] : 0;
    __syncthreads();
    part[t] += v;
    __syncthreads();
  }
  int run = part[t] - s;
  for (int i = base; i < end; ++i) {
    off[i] = run;
    run += cnt[i];
  }
  if (t == 1023) off[n] = part[1023];
}

// ---------------- CSR fill, XCD-partitioned by dst range --------------------
__global__ __launch_bounds__(256) void fill_part(
    const int* __restrict__ src_e, const int* __restrict__ dst_e,
    const int* __restrict__ src_p, const int* __restrict__ dst_p,
    const unsigned char* __restrict__ flag, const int* __restrict__ off_e,
    const int* __restrict__ off_p, int* __restrict__ cur_e,
    int* __restrict__ cur_p, int* __restrict__ csr_e,
    int* __restrict__ csr_p) {
  int xcd = blockIdx.x & 7;
  int lo = xcd * STU_PER_XCD, hi = lo + STU_PER_XCD;
  for (int c = blockIdx.x >> 3; c < NCHUNK; c += BGRP) {
    int t = (c << 8) + threadIdx.x;
    if (t < NE) {
      int d = dst_e[t];
      if (d >= lo && d < hi) {
        int p = atomicAdd(&cur_e[d], 1);
        csr_e[off_e[d] + p] = src_e[t];
      }
    } else if (t < NE + NEP) {
      int e = t - NE;
      int d = dst_p[e];
      if (d >= lo && d < hi && flag[d]) {
        int p = atomicAdd(&cur_p[d], 1);
        csr_p[off_p[d] + p] = src_p[e];
      }
    }
  }
}

// ------- X_sum/X_per/X_deep = exer @ {W_ue+W_deep, W_per, W_deep} -----------
// register-tiled: 256 thr, 32x128 tile/block, 4x4 regs/thread, k unrolled x4
#define TBM 32
__global__ __launch_bounds__(256) void transform_kernel(
    const float* __restrict__ exer, const float* __restrict__ W_ue,
    const float* __restrict__ W_per, const float* __restrict__ W_deep,
    float* __restrict__ X_sum, float* __restrict__ X_per,
    float* __restrict__ X_deep) {
  __shared__ float w[KNOW * KNOW];  // 64 KB
  __shared__ float a[TBM * KNOW];   // 16 KB
  int t = threadIdx.x;
  int which = blockIdx.y;
  float* outp = (which == 0) ? X_sum : (which == 1) ? X_per : X_deep;

  if (which == 0) {
#pragma unroll
    for (int i = t * 4; i < KNOW * KNOW; i += 1024) {
      float4 wa = *(const float4*)(W_ue + i);
      float4 wd = *(const float4*)(W_deep + i);
      float4 o = {wa.x + wd.x, wa.y + wd.y, wa.z + wd.z, wa.w + wd.w};
      *(float4*)(w + i) = o;
    }
  } else {
    const float* Ws = (which == 1) ? W_per : W_deep;
#pragma unroll
    for (int i = t * 4; i < KNOW * KNOW; i += 1024)
      *(float4*)(w + i) = *(const float4*)(Ws + i);
  }
  int r0 = blockIdx.x * TBM;
#pragma unroll
  for (int i = t * 4; i < TBM * KNOW; i += 1024)
    *(float4*)(a + i) = *(const float4*)(exer + (size_t)r0 * KNOW + i);
  __syncthreads();

  int cg = (t & 31) * 4;
  int rg = (t >> 5) * 4;
  float acc[4][4] = {};
  for (int k = 0; k < KNOW; k += 4) {
    float4 wv0 = *(const float4*)(w + (k + 0) * KNOW + cg);
    float4 wv1 = *(const float4*)(w + (k + 1) * KNOW + cg);
    float4 wv2 = *(const float4*)(w + (k + 2) * KNOW + cg);
    float4 wv3 = *(const float4*)(w + (k + 3) * KNOW + cg);
#pragma unroll
    for (int r = 0; r < 4; ++r) {
      float4 av = *(const float4*)(a + (rg + r) * KNOW + k);
      acc[r][0] += av.x * wv0.x + av.y * wv1.x + av.z * wv2.x + av.w * wv3.x;
      acc[r][1] += av.x * wv0.y + av.y * wv1.y + av.z * wv2.y + av.w * wv3.y;
      acc[r][2] += av.x * wv0.z + av.y * wv1.z + av.z * wv2.z + av.w * wv3.z;
      acc[r][3] += av.x * wv0.w + av.y * wv1.w + av.z * wv2.w + av.w * wv3.w;
    }
  }
#pragma unroll
  for (int r = 0; r < 4; ++r) {
    float4 o = {acc[r][0], acc[r][1], acc[r][2], acc[r][3]};
    *(float4*)(outp + (size_t)(r0 + rg + r) * KNOW + cg) = o;
  }
}

// ---------------- stu2 = stu_emb + mean(X_sum rows over CSR_e) --------------
__global__ __launch_bounds__(128) void stu2_gather(
    const float* __restrict__ stu_emb, const float* __restrict__ X_sum,
    const int* __restrict__ csr, const int* __restrict__ off,
    float* __restrict__ out) {
  int s = blockIdx.x;
  int k = threadIdx.x;
  int b = off[s], e = off[s + 1];
  float acc = 0.0f;
  int i = b;
  for (; i + 4 <= e; i += 4) {
    int s0 = csr[i], s1 = csr[i + 1], s2 = csr[i + 2], s3 = csr[i + 3];
    acc += X_sum[(size_t)s0 * KNOW + k];
    acc += X_sum[(size_t)s1 * KNOW + k];
    acc += X_sum[(size_t)s2 * KNOW + k];
    acc += X_sum[(size_t)s3 * KNOW + k];
  }
  for (; i < e; ++i) acc += X_sum[(size_t)csr[i] * KNOW + k];
  float inv = 1.0f / fmaxf((float)(e - b), 1.0f);
  out[(size_t)s * KNOW + k] = stu_emb[(size_t)s * KNOW + k] + acc * inv;
}

// ---------------- batch: pure gathers, normalize, write n1/n2 ---------------
__global__ __launch_bounds__(128) void batch_kernel(
    const float* __restrict__ stu_emb, const float* __restrict__ stu2,
    const float* __restrict__ X_per, const float* __restrict__ X_deep,
    const int* __restrict__ csr_p, const int* __restrict__ off_p,
    const int* __restrict__ csr_e, const int* __restrict__ off_e,
    const int* __restrict__ stu_id, float* __restrict__ n1,
    float* __restrict__ n2) {
  __shared__ float red[128];
  int i = blockIdx.x;
  int k = threadIdx.x;
  int sid = stu_id[i];

  int b = off_p[sid], e = off_p[sid + 1];
  float accp = 0.0f;
  int j = b;
  for (; j + 4 <= e; j += 4) {
    int s0 = csr_p[j], s1 = csr_p[j + 1], s2 = csr_p[j + 2], s3 = csr_p[j + 3];
    accp += X_per[(size_t)s0 * KNOW + k];
    accp += X_per[(size_t)s1 * KNOW + k];
    accp += X_per[(size_t)s2 * KNOW + k];
    accp += X_per[(size_t)s3 * KNOW + k];
  }
  for (; j < e; ++j) accp += X_per[(size_t)csr_p[j] * KNOW + k];
  accp /= fmaxf((float)(e - b), 1.0f);

  int b2i = off_e[sid], e2i = off_e[sid + 1];
  float accd = 0.0f;
  j = b2i;
  for (; j + 4 <= e2i; j += 4) {
    int s0 = csr_e[j], s1 = csr_e[j + 1], s2 = csr_e[j + 2], s3 = csr_e[j + 3];
    accd += X_deep[(size_t)s0 * KNOW + k];
    accd += X_deep[(size_t)s1 * KNOW + k];
    accd += X_deep[(size_t)s2 * KNOW + k];
    accd += X_deep[(size_t)s3 * KNOW + k];
  }
  for (; j < e2i; ++j) accd += X_deep[(size_t)csr_e[j] * KNOW + k];
  accd /= fmaxf((float)(e2i - b2i), 1.0f);

  float b1 = stu2[(size_t)sid * KNOW + k];
  float b2 = stu_emb[(size_t)sid * KNOW + k] + accp + accd;

  red[k] = b1 * b1;
  __syncthreads();
  for (int s = 64; s > 0; s >>= 1) {
    if (k < s) red[k] += red[k + s];
    __syncthreads();
  }
  float norm1 = sqrtf(red[0]);
  __syncthreads();
  red[k] = b2 * b2;
  __syncthreads();
  for (int s = 64; s > 0; s >>= 1) {
    if (k < s) red[k] += red[k + s];
    __syncthreads();
  }
  float norm2 = sqrtf(red[0]);

  n1[(size_t)i * KNOW + k] = b1 / norm1;
  n2[(size_t)i * KNOW + k] = b2 / norm2;
}

// ---------------- S2[k] = sum_i n2[i][k] (low-contention) -------------------
__global__ __launch_bounds__(128) void s2_reduce(const float* __restrict__ n2,
                                                 float* __restrict__ S2) {
  int k = threadIdx.x;
  int r0 = blockIdx.x * (BATCH / 64);
  float acc = 0.0f;
  for (int r = 0; r < BATCH / 64; ++r) acc += n2[(size_t)(r0 + r) * KNOW + k];
  atomicAdd(&S2[k], acc);
}

// ---------------- loss ----------------
__global__ __launch_bounds__(128) void loss_kernel(
    const float* __restrict__ n1, const float* __restrict__ n2,
    const float* __restrict__ S2, float* __restrict__ loss) {
  __shared__ float r1[128], r2[128];
  int i = blockIdx.x;
  int k = threadIdx.x;
  float a = n1[(size_t)i * KNOW + k];
  r1[k] = a * n2[(size_t)i * KNOW + k];
  r2[k] = a * S2[k];
  __syncthreads();
  for (int s = 64; s > 0; s >>= 1) {
    if (k < s) {
      r1[k] += r1[k + s];
      r2[k] += r2[k + s];
    }
    __syncthreads();
  }
  if (k == 0) {
    float diag = r1[0] * SOFT_INV;
    float rs = r2[0] * SOFT_INV;
    float ratio = expf(diag) / (rs + EPS);
    float li = -logf(fmaxf(ratio, EPS));
    atomicAdd(loss, li);
  }
}

__global__ void finalize_kernel(const float* __restrict__ loss,
                                float* __restrict__ out) {
  out[(size_t)STU_N * KNOW] = loss[0] * (1.0f / (float)BATCH);
}

extern "C" void kernel_launch(void* const* d_in, const int* in_sizes, int n_in,
                              void* d_out, int out_size, void* d_ws,
                              size_t ws_size, hipStream_t stream) {
  const float* stu_emb = (const float*)d_in[0];
  const float* exer_emb = (const float*)d_in[1];
  const float* W_ue = (const float*)d_in[2];
  const float* W_ue_per = (const float*)d_in[3];
  const float* W_deep = (const float*)d_in[4];
  const int* src_e = (const int*)d_in[5];
  const int* dst_e = (const int*)d_in[6];
  const int* src_p = (const int*)d_in[7];
  const int* dst_p = (const int*)d_in[8];
  const int* stu_id = (const int*)d_in[9];
  float* out = (float*)d_out;

  // ---- workspace layout (4-byte units) ----
  char* wsb = (char*)d_ws;
  // zeroed region first
  int* cnt_e = (int*)wsb;               // 50,000
  int* cnt_p = cnt_e + STU_N;           // 50,000
  int* cur_e = cnt_p + STU_N;           // 50,000
  int* cur_p = cur_e + STU_N;           // 50,000
  float* S2 = (float*)(cur_p + STU_N);  // 128
  float* loss = S2 + KNOW;              // 1
  unsigned char* flag = (unsigned char*)(loss + 1);  // 50,000 bytes
  size_t zero_bytes = (size_t)(flag + ((STU_N + 3) & ~3) - (unsigned char*)wsb);
  // rest (fully overwritten each call)
  float* X_sum = (float*)(flag + ((STU_N + 3) & ~3));   // 2,560,000
  float* X_per = X_sum + (size_t)EXER_N * KNOW;         // 2,560,000
  float* X_deep = X_per + (size_t)EXER_N * KNOW;        // 2,560,000
  int* off_e = (int*)(X_deep + (size_t)EXER_N * KNOW);  // 50,001
  int* off_p = off_e + STU_N + 1;                       // 50,001
  int* csr_e = off_p + STU_N + 1;                       // 1,000,000
  int* csr_p = csr_e + NE;                              // 950,000
  float* n1 = (float*)(csr_p + NEP);                    // 1,048,576
  float* n2 = n1 + (size_t)BATCH * KNOW;                // 1,048,576

  hipMemsetAsync(d_ws, 0, zero_bytes, stream);

  set_flags<<<(BATCH + 255) / 256, 256, 0, stream>>>(stu_id, flag);

  // exercise-level transforms (independent of CSR)
  {
    dim3 grid(EXER_N / TBM, 3);
    transform_kernel<<<grid, 256, 0, stream>>>(exer_emb, W_ue, W_ue_per,
                                               W_deep, X_sum, X_per, X_deep);
  }

  // CSR build, XCD-partitioned
  count_part<<<NXCD * BGRP, 256, 0, stream>>>(dst_e, dst_p, flag, cnt_e,
                                              cnt_p);
  scan_both<<<2, 1024, 0, stream>>>(cnt_e, cnt_p, off_e, off_p);
  fill_part<<<NXCD * BGRP, 256, 0, stream>>>(src_e, dst_e, src_p, dst_p, flag,
                                             off_e, off_p, cur_e, cur_p, csr_e,
                                             csr_p);

  // stu2 = stu_emb + mean(X_sum over CSR_e)
  stu2_gather<<<STU_N, 128, 0, stream>>>(stu_emb, X_sum, csr_e, off_e, out);

  // batch path — pure gathers
  batch_kernel<<<BATCH, 128, 0, stream>>>(stu_emb, out, X_per, X_deep, csr_p,
                                          off_p, csr_e, off_e, stu_id, n1, n2);

  s2_reduce<<<64, 128, 0, stream>>>(n2, S2);

  loss_kernel<<<BATCH, 128, 0, stream>>>(n1, n2, S2, loss);

  finalize_kernel<<<1, 1, 0, stream>>>(loss, out);
}

// Round 6
// 461.752 us; speedup vs baseline: 8.5966x; 1.1861x over previous
//
#include <hip/hip_runtime.h>
#include <math.h>

#define KNOW 128
#define STU_N 50000
#define EXER_N 20000
#define BATCH 8192
#define NE 1000000
#define NEP 950000
#define SOFT_INV 5.0f   // 1/0.2
#define EPS 1e-8f

#define NXCD 8
#define STU_PER_XCD (STU_N / NXCD)  // 6250
#define NCHUNK ((NE + NEP + 255) / 256)
#define BGRP 952  // block-groups per XCD for edge kernels

// ---------------- flag sampled students ----------------
__global__ void set_flags(const int* __restrict__ stu_id,
                          unsigned char* __restrict__ flag) {
  int i = blockIdx.x * blockDim.x + threadIdx.x;
  if (i < BATCH) flag[stu_id[i]] = 1;
}

// ---------------- CSR count, XCD-partitioned by dst range -------------------
__global__ __launch_bounds__(256) void count_part(
    const int* __restrict__ dst_e, const int* __restrict__ dst_p,
    const unsigned char* __restrict__ flag, int* __restrict__ cnt_e,
    int* __restrict__ cnt_p) {
  int xcd = blockIdx.x & 7;
  int lo = xcd * STU_PER_XCD, hi = lo + STU_PER_XCD;
  for (int c = blockIdx.x >> 3; c < NCHUNK; c += BGRP) {
    int t = (c << 8) + threadIdx.x;
    if (t < NE) {
      int d = dst_e[t];
      if (d >= lo && d < hi) atomicAdd(&cnt_e[d], 1);
    } else if (t < NE + NEP) {
      int d = dst_p[t - NE];
      if (d >= lo && d < hi && flag[d]) atomicAdd(&cnt_p[d], 1);
    }
  }
}

// ---------------- CSR exclusive scan (block 0: e, block 1: p) ---------------
__global__ __launch_bounds__(1024) void scan_both(const int* __restrict__ cnt_e,
                                                  const int* __restrict__ cnt_p,
                                                  int* __restrict__ off_e,
                                                  int* __restrict__ off_p) {
  __shared__ int part[1024];
  const int* cnt = (blockIdx.x == 0) ? cnt_e : cnt_p;
  int* off = (blockIdx.x == 0) ? off_e : off_p;
  const int n = STU_N;
  int t = threadIdx.x;
  int per = (n + 1023) >> 10;
  int base = t * per;
  int end = base + per;
  if (end > n) end = n;
  int s = 0;
  for (int i = base; i < end; ++i) s += cnt[i];
  part[t] = s;
  __syncthreads();
  for (int d = 1; d < 1024; d <<= 1) {
    int v = (t >= d) ? part[t - d] : 0;
    __syncthreads();
    part[t] += v;
    __syncthreads();
  }
  int run = part[t] - s;
  for (int i = base; i < end; ++i) {
    off[i] = run;
    run += cnt[i];
  }
  if (t == 1023) off[n] = part[1023];
}

// ---------------- CSR fill, XCD-partitioned by dst range --------------------
__global__ __launch_bounds__(256) void fill_part(
    const int* __restrict__ src_e, const int* __restrict__ dst_e,
    const int* __restrict__ src_p, const int* __restrict__ dst_p,
    const unsigned char* __restrict__ flag, const int* __restrict__ off_e,
    const int* __restrict__ off_p, int* __restrict__ cur_e,
    int* __restrict__ cur_p, int* __restrict__ csr_e,
    int* __restrict__ csr_p) {
  int xcd = blockIdx.x & 7;
  int lo = xcd * STU_PER_XCD, hi = lo + STU_PER_XCD;
  for (int c = blockIdx.x >> 3; c < NCHUNK; c += BGRP) {
    int t = (c << 8) + threadIdx.x;
    if (t < NE) {
      int d = dst_e[t];
      if (d >= lo && d < hi) {
        int p = atomicAdd(&cur_e[d], 1);
        csr_e[off_e[d] + p] = src_e[t];
      }
    } else if (t < NE + NEP) {
      int e = t - NE;
      int d = dst_p[e];
      if (d >= lo && d < hi && flag[d]) {
        int p = atomicAdd(&cur_p[d], 1);
        csr_p[off_p[d] + p] = src_p[e];
      }
    }
  }
}

// ------- X_sum/X_per/X_deep = exer @ {W_ue+W_deep, W_per, W_deep} -----------
#define TBM 32
__global__ __launch_bounds__(256) void transform_kernel(
    const float* __restrict__ exer, const float* __restrict__ W_ue,
    const float* __restrict__ W_per, const float* __restrict__ W_deep,
    float* __restrict__ X_sum, float* __restrict__ X_per,
    float* __restrict__ X_deep) {
  __shared__ float w[KNOW * KNOW];  // 64 KB
  __shared__ float a[TBM * KNOW];   // 16 KB
  int t = threadIdx.x;
  int which = blockIdx.y;
  float* outp = (which == 0) ? X_sum : (which == 1) ? X_per : X_deep;

  if (which == 0) {
#pragma unroll
    for (int i = t * 4; i < KNOW * KNOW; i += 1024) {
      float4 wa = *(const float4*)(W_ue + i);
      float4 wd = *(const float4*)(W_deep + i);
      float4 o = {wa.x + wd.x, wa.y + wd.y, wa.z + wd.z, wa.w + wd.w};
      *(float4*)(w + i) = o;
    }
  } else {
    const float* Ws = (which == 1) ? W_per : W_deep;
#pragma unroll
    for (int i = t * 4; i < KNOW * KNOW; i += 1024)
      *(float4*)(w + i) = *(const float4*)(Ws + i);
  }
  int r0 = blockIdx.x * TBM;
#pragma unroll
  for (int i = t * 4; i < TBM * KNOW; i += 1024)
    *(float4*)(a + i) = *(const float4*)(exer + (size_t)r0 * KNOW + i);
  __syncthreads();

  int cg = (t & 31) * 4;
  int rg = (t >> 5) * 4;
  float acc[4][4] = {};
  for (int k = 0; k < KNOW; k += 4) {
    float4 wv0 = *(const float4*)(w + (k + 0) * KNOW + cg);
    float4 wv1 = *(const float4*)(w + (k + 1) * KNOW + cg);
    float4 wv2 = *(const float4*)(w + (k + 2) * KNOW + cg);
    float4 wv3 = *(const float4*)(w + (k + 3) * KNOW + cg);
#pragma unroll
    for (int r = 0; r < 4; ++r) {
      float4 av = *(const float4*)(a + (rg + r) * KNOW + k);
      acc[r][0] += av.x * wv0.x + av.y * wv1.x + av.z * wv2.x + av.w * wv3.x;
      acc[r][1] += av.x * wv0.y + av.y * wv1.y + av.z * wv2.y + av.w * wv3.y;
      acc[r][2] += av.x * wv0.z + av.y * wv1.z + av.z * wv2.z + av.w * wv3.z;
      acc[r][3] += av.x * wv0.w + av.y * wv1.w + av.z * wv2.w + av.w * wv3.w;
    }
  }
#pragma unroll
  for (int r = 0; r < 4; ++r) {
    float4 o = {acc[r][0], acc[r][1], acc[r][2], acc[r][3]};
    *(float4*)(outp + (size_t)(r0 + rg + r) * KNOW + cg) = o;
  }
}

// ------- stu2 = stu_emb + mean(X_sum rows over CSR_e), float4 gather --------
__global__ __launch_bounds__(128) void stu2_gather(
    const float* __restrict__ stu_emb, const float* __restrict__ X_sum,
    const int* __restrict__ csr, const int* __restrict__ off,
    float* __restrict__ out) {
  __shared__ float4 part[128];
  int s = blockIdx.x;
  int t = threadIdx.x;
  int c = t & 31;  // float4 chunk within row
  int g = t >> 5;  // edge group 0..3
  int b = off[s], e = off[s + 1];
  float4 acc = {0.f, 0.f, 0.f, 0.f};
  int i = b + g;
  for (; i + 4 < e; i += 8) {
    const float4 v0 = *(const float4*)(X_sum + (size_t)csr[i] * KNOW + c * 4);
    const float4 v1 =
        *(const float4*)(X_sum + (size_t)csr[i + 4] * KNOW + c * 4);
    acc.x += v0.x + v1.x;
    acc.y += v0.y + v1.y;
    acc.z += v0.z + v1.z;
    acc.w += v0.w + v1.w;
  }
  if (i < e) {
    const float4 v = *(const float4*)(X_sum + (size_t)csr[i] * KNOW + c * 4);
    acc.x += v.x;
    acc.y += v.y;
    acc.z += v.z;
    acc.w += v.w;
  }
  part[t] = acc;
  __syncthreads();
  if (t < 32) {
    float4 a0 = part[t], a1 = part[t + 32], a2 = part[t + 64], a3 = part[t + 96];
    float inv = 1.0f / fmaxf((float)(e - b), 1.0f);
    float4 se = *(const float4*)(stu_emb + (size_t)s * KNOW + t * 4);
    float4 o;
    o.x = se.x + (a0.x + a1.x + a2.x + a3.x) * inv;
    o.y = se.y + (a0.y + a1.y + a2.y + a3.y) * inv;
    o.z = se.z + (a0.z + a1.z + a2.z + a3.z) * inv;
    o.w = se.w + (a0.w + a1.w + a2.w + a3.w) * inv;
    *(float4*)(out + (size_t)s * KNOW + t * 4) = o;
  }
}

// ---- batch: gathers, normalize, write n1/n2, diag = n1·n2 ------------------
__global__ __launch_bounds__(128) void batch_kernel(
    const float* __restrict__ stu_emb, const float* __restrict__ stu2,
    const float* __restrict__ X_per, const float* __restrict__ X_deep,
    const int* __restrict__ csr_p, const int* __restrict__ off_p,
    const int* __restrict__ csr_e, const int* __restrict__ off_e,
    const int* __restrict__ stu_id, float* __restrict__ n1,
    float* __restrict__ n2, float* __restrict__ diag) {
  __shared__ float red[128];
  int i = blockIdx.x;
  int k = threadIdx.x;
  int sid = stu_id[i];

  int b = off_p[sid], e = off_p[sid + 1];
  float accp = 0.0f;
  int j = b;
  for (; j + 4 <= e; j += 4) {
    int s0 = csr_p[j], s1 = csr_p[j + 1], s2 = csr_p[j + 2], s3 = csr_p[j + 3];
    accp += X_per[(size_t)s0 * KNOW + k];
    accp += X_per[(size_t)s1 * KNOW + k];
    accp += X_per[(size_t)s2 * KNOW + k];
    accp += X_per[(size_t)s3 * KNOW + k];
  }
  for (; j < e; ++j) accp += X_per[(size_t)csr_p[j] * KNOW + k];
  accp /= fmaxf((float)(e - b), 1.0f);

  int b2i = off_e[sid], e2i = off_e[sid + 1];
  float accd = 0.0f;
  j = b2i;
  for (; j + 4 <= e2i; j += 4) {
    int s0 = csr_e[j], s1 = csr_e[j + 1], s2 = csr_e[j + 2], s3 = csr_e[j + 3];
    accd += X_deep[(size_t)s0 * KNOW + k];
    accd += X_deep[(size_t)s1 * KNOW + k];
    accd += X_deep[(size_t)s2 * KNOW + k];
    accd += X_deep[(size_t)s3 * KNOW + k];
  }
  for (; j < e2i; ++j) accd += X_deep[(size_t)csr_e[j] * KNOW + k];
  accd /= fmaxf((float)(e2i - b2i), 1.0f);

  float b1 = stu2[(size_t)sid * KNOW + k];
  float b2 = stu_emb[(size_t)sid * KNOW + k] + accp + accd;

  red[k] = b1 * b1;
  __syncthreads();
  for (int s = 64; s > 0; s >>= 1) {
    if (k < s) red[k] += red[k + s];
    __syncthreads();
  }
  float norm1 = sqrtf(red[0]);
  __syncthreads();
  red[k] = b2 * b2;
  __syncthreads();
  for (int s = 64; s > 0; s >>= 1) {
    if (k < s) red[k] += red[k + s];
    __syncthreads();
  }
  float norm2 = sqrtf(red[0]);

  float v1 = b1 / norm1;
  float v2 = b2 / norm2;
  n1[(size_t)i * KNOW + k] = v1;
  n2[(size_t)i * KNOW + k] = v2;

  __syncthreads();
  red[k] = v1 * v2;
  __syncthreads();
  for (int s = 64; s > 0; s >>= 1) {
    if (k < s) red[k] += red[k + s];
    __syncthreads();
  }
  if (k == 0) diag[i] = red[0];
}

// ---------------- S2[k] = sum_i n2[i][k] (low-contention) -------------------
__global__ __launch_bounds__(128) void s2_reduce(const float* __restrict__ n2,
                                                 float* __restrict__ S2) {
  int k = threadIdx.x;
  int r0 = blockIdx.x * (BATCH / 64);
  float acc = 0.0f;
  for (int r = 0; r < BATCH / 64; ++r) acc += n2[(size_t)(r0 + r) * KNOW + k];
  atomicAdd(&S2[k], acc);
}

// ------ loss2: rowsum_i = n1_i·S2 via wave per row; 1 atomic per wave -------
#define L2BLKS 64
__global__ __launch_bounds__(256) void loss2(const float* __restrict__ n1,
                                             const float* __restrict__ diag,
                                             const float* __restrict__ S2,
                                             float* __restrict__ loss) {
  __shared__ float s2s[KNOW];
  int t = threadIdx.x;
  if (t < KNOW) s2s[t] = S2[t];
  __syncthreads();
  int wave = t >> 6, lane = t & 63;
  const int rows_per_wave = BATCH / (L2BLKS * 4);  // 32
  int r0 = (blockIdx.x * 4 + wave) * rows_per_wave;
  float acc = 0.0f;
  for (int r = r0; r < r0 + rows_per_wave; ++r) {
    float v = n1[(size_t)r * KNOW + lane] * s2s[lane] +
              n1[(size_t)r * KNOW + 64 + lane] * s2s[64 + lane];
#pragma unroll
    for (int off = 32; off > 0; off >>= 1) v += __shfl_down(v, off);
    if (lane == 0) {
      float rs = v * SOFT_INV;
      float dg = diag[r] * SOFT_INV;
      float ratio = expf(dg) / (rs + EPS);
      acc += -logf(fmaxf(ratio, EPS));
    }
  }
  if (lane == 0) atomicAdd(loss, acc);
}

__global__ void finalize_kernel(const float* __restrict__ loss,
                                float* __restrict__ out) {
  out[(size_t)STU_N * KNOW] = loss[0] * (1.0f / (float)BATCH);
}

extern "C" void kernel_launch(void* const* d_in, const int* in_sizes, int n_in,
                              void* d_out, int out_size, void* d_ws,
                              size_t ws_size, hipStream_t stream) {
  const float* stu_emb = (const float*)d_in[0];
  const float* exer_emb = (const float*)d_in[1];
  const float* W_ue = (const float*)d_in[2];
  const float* W_ue_per = (const float*)d_in[3];
  const float* W_deep = (const float*)d_in[4];
  const int* src_e = (const int*)d_in[5];
  const int* dst_e = (const int*)d_in[6];
  const int* src_p = (const int*)d_in[7];
  const int* dst_p = (const int*)d_in[8];
  const int* stu_id = (const int*)d_in[9];
  float* out = (float*)d_out;

  // ---- workspace layout ----
  char* wsb = (char*)d_ws;
  // zeroed region first
  int* cnt_e = (int*)wsb;               // 50,000
  int* cnt_p = cnt_e + STU_N;           // 50,000
  int* cur_e = cnt_p + STU_N;           // 50,000
  int* cur_p = cur_e + STU_N;           // 50,000
  float* S2 = (float*)(cur_p + STU_N);  // 128
  float* loss = S2 + KNOW;              // 1
  unsigned char* flag = (unsigned char*)(loss + 1);  // 50,000 bytes
  size_t zero_bytes = (size_t)(flag + ((STU_N + 3) & ~3) - (unsigned char*)wsb);
  // rest (fully overwritten each call)
  float* X_sum = (float*)(flag + ((STU_N + 3) & ~3));   // 2,560,000
  float* X_per = X_sum + (size_t)EXER_N * KNOW;         // 2,560,000
  float* X_deep = X_per + (size_t)EXER_N * KNOW;        // 2,560,000
  int* off_e = (int*)(X_deep + (size_t)EXER_N * KNOW);  // 50,001
  int* off_p = off_e + STU_N + 1;                       // 50,001
  int* csr_e = off_p + STU_N + 1;                       // 1,000,000
  int* csr_p = csr_e + NE;                              // 950,000
  float* n1 = (float*)(csr_p + NEP);                    // 1,048,576
  float* n2 = n1 + (size_t)BATCH * KNOW;                // 1,048,576
  float* diag = n2 + (size_t)BATCH * KNOW;              // 8,192

  hipMemsetAsync(d_ws, 0, zero_bytes, stream);

  set_flags<<<(BATCH + 255) / 256, 256, 0, stream>>>(stu_id, flag);

  {
    dim3 grid(EXER_N / TBM, 3);
    transform_kernel<<<grid, 256, 0, stream>>>(exer_emb, W_ue, W_ue_per,
                                               W_deep, X_sum, X_per, X_deep);
  }

  count_part<<<NXCD * BGRP, 256, 0, stream>>>(dst_e, dst_p, flag, cnt_e,
                                              cnt_p);
  scan_both<<<2, 1024, 0, stream>>>(cnt_e, cnt_p, off_e, off_p);
  fill_part<<<NXCD * BGRP, 256, 0, stream>>>(src_e, dst_e, src_p, dst_p, flag,
                                             off_e, off_p, cur_e, cur_p, csr_e,
                                             csr_p);

  stu2_gather<<<STU_N, 128, 0, stream>>>(stu_emb, X_sum, csr_e, off_e, out);

  batch_kernel<<<BATCH, 128, 0, stream>>>(stu_emb, out, X_per, X_deep, csr_p,
                                          off_p, csr_e, off_e, stu_id, n1, n2,
                                          diag);

  s2_reduce<<<64, 128, 0, stream>>>(n2, S2);

  loss2<<<L2BLKS, 256, 0, stream>>>(n1, diag, S2, loss);

  finalize_kernel<<<1, 1, 0, stream>>>(loss, out);
}

// Round 7
// 398.225 us; speedup vs baseline: 9.9679x; 1.1595x over previous
//
#include <hip/hip_runtime.h>
#include <math.h>

#define KNOW 128
#define STU_N 50000
#define EXER_N 20000
#define BATCH 8192
#define NE 1000000
#define NEP 950000
#define SOFT_INV 5.0f   // 1/0.2
#define EPS 1e-8f

#define NXCD 8
#define STU_PER_XCD (STU_N / NXCD)  // 6250
#define NCHUNK ((NE + NEP + 255) / 256)
#define BGRP 952  // block-groups per XCD for edge kernels

#define NTILES ((STU_N + 255) / 256)  // 196

// ---------------- flag sampled students ----------------
__global__ void set_flags(const int* __restrict__ stu_id,
                          unsigned char* __restrict__ flag) {
  int i = blockIdx.x * blockDim.x + threadIdx.x;
  if (i < BATCH) flag[stu_id[i]] = 1;
}

// ---------------- CSR count, XCD-partitioned by dst range -------------------
__global__ __launch_bounds__(256) void count_part(
    const int* __restrict__ dst_e, const int* __restrict__ dst_p,
    const unsigned char* __restrict__ flag, int* __restrict__ cnt_e,
    int* __restrict__ cnt_p) {
  int xcd = blockIdx.x & 7;
  int lo = xcd * STU_PER_XCD, hi = lo + STU_PER_XCD;
  for (int c = blockIdx.x >> 3; c < NCHUNK; c += BGRP) {
    int t = (c << 8) + threadIdx.x;
    if (t < NE) {
      int d = dst_e[t];
      if (d >= lo && d < hi) atomicAdd(&cnt_e[d], 1);
    } else if (t < NE + NEP) {
      int d = dst_p[t - NE];
      if (d >= lo && d < hi && flag[d]) atomicAdd(&cnt_p[d], 1);
    }
  }
}

// ---------------- hierarchical scan, phase A: tile sums ---------------------
__global__ __launch_bounds__(256) void tile_sum_kernel(
    const int* __restrict__ cnt_e, const int* __restrict__ cnt_p,
    int* __restrict__ tsum) {
  __shared__ int red[256];
  const int* cnt = (blockIdx.y == 0) ? cnt_e : cnt_p;
  int i = blockIdx.x * 256 + threadIdx.x;
  red[threadIdx.x] = (i < STU_N) ? cnt[i] : 0;
  __syncthreads();
  for (int s = 128; s > 0; s >>= 1) {
    if (threadIdx.x < s) red[threadIdx.x] += red[threadIdx.x + s];
    __syncthreads();
  }
  if (threadIdx.x == 0) tsum[blockIdx.y * NTILES + blockIdx.x] = red[0];
}

// ---------------- phase B: exclusive-scan the tile sums (in place) ----------
__global__ __launch_bounds__(256) void scan_tiles_kernel(int* __restrict__ tsum) {
  __shared__ int sh[256];
  int* ts = tsum + blockIdx.x * NTILES;
  int t = threadIdx.x;
  int v = (t < NTILES) ? ts[t] : 0;
  sh[t] = v;
  __syncthreads();
  for (int d = 1; d < 256; d <<= 1) {
    int u = (t >= d) ? sh[t - d] : 0;
    __syncthreads();
    sh[t] += u;
    __syncthreads();
  }
  if (t < NTILES) ts[t] = sh[t] - v;  // exclusive
}

// ---------------- phase C: per-tile scan + offset, write off ----------------
__global__ __launch_bounds__(256) void tile_scan_kernel(
    const int* __restrict__ cnt_e, const int* __restrict__ cnt_p,
    const int* __restrict__ tsum, int* __restrict__ off_e,
    int* __restrict__ off_p) {
  __shared__ int sh[256];
  const int* cnt = (blockIdx.y == 0) ? cnt_e : cnt_p;
  int* off = (blockIdx.y == 0) ? off_e : off_p;
  int tile_off = tsum[blockIdx.y * NTILES + blockIdx.x];
  int t = threadIdx.x;
  int i = blockIdx.x * 256 + t;
  int v = (i < STU_N) ? cnt[i] : 0;
  sh[t] = v;
  __syncthreads();
  for (int d = 1; d < 256; d <<= 1) {
    int u = (t >= d) ? sh[t - d] : 0;
    __syncthreads();
    sh[t] += u;
    __syncthreads();
  }
  if (i < STU_N) off[i] = tile_off + sh[t] - v;  // exclusive
  if (i == STU_N - 1) off[STU_N] = tile_off + sh[t];  // total
}

// ---------------- CSR fill, XCD-partitioned by dst range --------------------
__global__ __launch_bounds__(256) void fill_part(
    const int* __restrict__ src_e, const int* __restrict__ dst_e,
    const int* __restrict__ src_p, const int* __restrict__ dst_p,
    const unsigned char* __restrict__ flag, const int* __restrict__ off_e,
    const int* __restrict__ off_p, int* __restrict__ cur_e,
    int* __restrict__ cur_p, int* __restrict__ csr_e,
    int* __restrict__ csr_p) {
  int xcd = blockIdx.x & 7;
  int lo = xcd * STU_PER_XCD, hi = lo + STU_PER_XCD;
  for (int c = blockIdx.x >> 3; c < NCHUNK; c += BGRP) {
    int t = (c << 8) + threadIdx.x;
    if (t < NE) {
      int d = dst_e[t];
      if (d >= lo && d < hi) {
        int p = atomicAdd(&cur_e[d], 1);
        csr_e[off_e[d] + p] = src_e[t];
      }
    } else if (t < NE + NEP) {
      int e = t - NE;
      int d = dst_p[e];
      if (d >= lo && d < hi && flag[d]) {
        int p = atomicAdd(&cur_p[d], 1);
        csr_p[off_p[d] + p] = src_p[e];
      }
    }
  }
}

// ------- X_sum/X_per/X_deep = exer @ {W_ue+W_deep, W_per, W_deep} -----------
#define TBM 32
__global__ __launch_bounds__(256) void transform_kernel(
    const float* __restrict__ exer, const float* __restrict__ W_ue,
    const float* __restrict__ W_per, const float* __restrict__ W_deep,
    float* __restrict__ X_sum, float* __restrict__ X_per,
    float* __restrict__ X_deep) {
  __shared__ float w[KNOW * KNOW];  // 64 KB
  __shared__ float a[TBM * KNOW];   // 16 KB
  int t = threadIdx.x;
  int which = blockIdx.y;
  float* outp = (which == 0) ? X_sum : (which == 1) ? X_per : X_deep;

  if (which == 0) {
#pragma unroll
    for (int i = t * 4; i < KNOW * KNOW; i += 1024) {
      float4 wa = *(const float4*)(W_ue + i);
      float4 wd = *(const float4*)(W_deep + i);
      float4 o = {wa.x + wd.x, wa.y + wd.y, wa.z + wd.z, wa.w + wd.w};
      *(float4*)(w + i) = o;
    }
  } else {
    const float* Ws = (which == 1) ? W_per : W_deep;
#pragma unroll
    for (int i = t * 4; i < KNOW * KNOW; i += 1024)
      *(float4*)(w + i) = *(const float4*)(Ws + i);
  }
  int r0 = blockIdx.x * TBM;
#pragma unroll
  for (int i = t * 4; i < TBM * KNOW; i += 1024)
    *(float4*)(a + i) = *(const float4*)(exer + (size_t)r0 * KNOW + i);
  __syncthreads();

  int cg = (t & 31) * 4;
  int rg = (t >> 5) * 4;
  float acc[4][4] = {};
  for (int k = 0; k < KNOW; k += 4) {
    float4 wv0 = *(const float4*)(w + (k + 0) * KNOW + cg);
    float4 wv1 = *(const float4*)(w + (k + 1) * KNOW + cg);
    float4 wv2 = *(const float4*)(w + (k + 2) * KNOW + cg);
    float4 wv3 = *(const float4*)(w + (k + 3) * KNOW + cg);
#pragma unroll
    for (int r = 0; r < 4; ++r) {
      float4 av = *(const float4*)(a + (rg + r) * KNOW + k);
      acc[r][0] += av.x * wv0.x + av.y * wv1.x + av.z * wv2.x + av.w * wv3.x;
      acc[r][1] += av.x * wv0.y + av.y * wv1.y + av.z * wv2.y + av.w * wv3.y;
      acc[r][2] += av.x * wv0.z + av.y * wv1.z + av.z * wv2.z + av.w * wv3.z;
      acc[r][3] += av.x * wv0.w + av.y * wv1.w + av.z * wv2.w + av.w * wv3.w;
    }
  }
#pragma unroll
  for (int r = 0; r < 4; ++r) {
    float4 o = {acc[r][0], acc[r][1], acc[r][2], acc[r][3]};
    *(float4*)(outp + (size_t)(r0 + rg + r) * KNOW + cg) = o;
  }
}

// ------- stu2 = stu_emb + mean(X_sum rows over CSR_e), float4 gather --------
__global__ __launch_bounds__(128) void stu2_gather(
    const float* __restrict__ stu_emb, const float* __restrict__ X_sum,
    const int* __restrict__ csr, const int* __restrict__ off,
    float* __restrict__ out) {
  __shared__ float4 part[128];
  int s = blockIdx.x;
  int t = threadIdx.x;
  int c = t & 31;  // float4 chunk within row
  int g = t >> 5;  // edge group 0..3
  int b = off[s], e = off[s + 1];
  float4 acc = {0.f, 0.f, 0.f, 0.f};
  int i = b + g;
  for (; i + 4 < e; i += 8) {
    const float4 v0 = *(const float4*)(X_sum + (size_t)csr[i] * KNOW + c * 4);
    const float4 v1 =
        *(const float4*)(X_sum + (size_t)csr[i + 4] * KNOW + c * 4);
    acc.x += v0.x + v1.x;
    acc.y += v0.y + v1.y;
    acc.z += v0.z + v1.z;
    acc.w += v0.w + v1.w;
  }
  if (i < e) {
    const float4 v = *(const float4*)(X_sum + (size_t)csr[i] * KNOW + c * 4);
    acc.x += v.x;
    acc.y += v.y;
    acc.z += v.z;
    acc.w += v.w;
  }
  part[t] = acc;
  __syncthreads();
  if (t < 32) {
    float4 a0 = part[t], a1 = part[t + 32], a2 = part[t + 64], a3 = part[t + 96];
    float inv = 1.0f / fmaxf((float)(e - b), 1.0f);
    float4 se = *(const float4*)(stu_emb + (size_t)s * KNOW + t * 4);
    float4 o;
    o.x = se.x + (a0.x + a1.x + a2.x + a3.x) * inv;
    o.y = se.y + (a0.y + a1.y + a2.y + a3.y) * inv;
    o.z = se.z + (a0.z + a1.z + a2.z + a3.z) * inv;
    o.w = se.w + (a0.w + a1.w + a2.w + a3.w) * inv;
    *(float4*)(out + (size_t)s * KNOW + t * 4) = o;
  }
}

// ---- batch: gathers, normalize, write n1/n2, diag = n1·n2 ------------------
__global__ __launch_bounds__(128) void batch_kernel(
    const float* __restrict__ stu_emb, const float* __restrict__ stu2,
    const float* __restrict__ X_per, const float* __restrict__ X_deep,
    const int* __restrict__ csr_p, const int* __restrict__ off_p,
    const int* __restrict__ csr_e, const int* __restrict__ off_e,
    const int* __restrict__ stu_id, float* __restrict__ n1,
    float* __restrict__ n2, float* __restrict__ diag) {
  __shared__ float red[128];
  int i = blockIdx.x;
  int k = threadIdx.x;
  int sid = stu_id[i];

  int b = off_p[sid], e = off_p[sid + 1];
  float accp = 0.0f;
  int j = b;
  for (; j + 4 <= e; j += 4) {
    int s0 = csr_p[j], s1 = csr_p[j + 1], s2 = csr_p[j + 2], s3 = csr_p[j + 3];
    accp += X_per[(size_t)s0 * KNOW + k];
    accp += X_per[(size_t)s1 * KNOW + k];
    accp += X_per[(size_t)s2 * KNOW + k];
    accp += X_per[(size_t)s3 * KNOW + k];
  }
  for (; j < e; ++j) accp += X_per[(size_t)csr_p[j] * KNOW + k];
  accp /= fmaxf((float)(e - b), 1.0f);

  int b2i = off_e[sid], e2i = off_e[sid + 1];
  float accd = 0.0f;
  j = b2i;
  for (; j + 4 <= e2i; j += 4) {
    int s0 = csr_e[j], s1 = csr_e[j + 1], s2 = csr_e[j + 2], s3 = csr_e[j + 3];
    accd += X_deep[(size_t)s0 * KNOW + k];
    accd += X_deep[(size_t)s1 * KNOW + k];
    accd += X_deep[(size_t)s2 * KNOW + k];
    accd += X_deep[(size_t)s3 * KNOW + k];
  }
  for (; j < e2i; ++j) accd += X_deep[(size_t)csr_e[j] * KNOW + k];
  accd /= fmaxf((float)(e2i - b2i), 1.0f);

  float b1 = stu2[(size_t)sid * KNOW + k];
  float b2 = stu_emb[(size_t)sid * KNOW + k] + accp + accd;

  red[k] = b1 * b1;
  __syncthreads();
  for (int s = 64; s > 0; s >>= 1) {
    if (k < s) red[k] += red[k + s];
    __syncthreads();
  }
  float norm1 = sqrtf(red[0]);
  __syncthreads();
  red[k] = b2 * b2;
  __syncthreads();
  for (int s = 64; s > 0; s >>= 1) {
    if (k < s) red[k] += red[k + s];
    __syncthreads();
  }
  float norm2 = sqrtf(red[0]);

  float v1 = b1 / norm1;
  float v2 = b2 / norm2;
  n1[(size_t)i * KNOW + k] = v1;
  n2[(size_t)i * KNOW + k] = v2;

  __syncthreads();
  red[k] = v1 * v2;
  __syncthreads();
  for (int s = 64; s > 0; s >>= 1) {
    if (k < s) red[k] += red[k + s];
    __syncthreads();
  }
  if (k == 0) diag[i] = red[0];
}

// ---------------- S2[k] = sum_i n2[i][k] (low-contention) -------------------
__global__ __launch_bounds__(128) void s2_reduce(const float* __restrict__ n2,
                                                 float* __restrict__ S2) {
  int k = threadIdx.x;
  int r0 = blockIdx.x * (BATCH / 64);
  float acc = 0.0f;
  for (int r = 0; r < BATCH / 64; ++r) acc += n2[(size_t)(r0 + r) * KNOW + k];
  atomicAdd(&S2[k], acc);
}

// ------ loss2: rowsum_i = n1_i·S2 via wave per row; 1 atomic per wave -------
#define L2BLKS 64
__global__ __launch_bounds__(256) void loss2(const float* __restrict__ n1,
                                             const float* __restrict__ diag,
                                             const float* __restrict__ S2,
                                             float* __restrict__ loss) {
  __shared__ float s2s[KNOW];
  int t = threadIdx.x;
  if (t < KNOW) s2s[t] = S2[t];
  __syncthreads();
  int wave = t >> 6, lane = t & 63;
  const int rows_per_wave = BATCH / (L2BLKS * 4);  // 32
  int r0 = (blockIdx.x * 4 + wave) * rows_per_wave;
  float acc = 0.0f;
  for (int r = r0; r < r0 + rows_per_wave; ++r) {
    float v = n1[(size_t)r * KNOW + lane] * s2s[lane] +
              n1[(size_t)r * KNOW + 64 + lane] * s2s[64 + lane];
#pragma unroll
    for (int off = 32; off > 0; off >>= 1) v += __shfl_down(v, off);
    if (lane == 0) {
      float rs = v * SOFT_INV;
      float dg = diag[r] * SOFT_INV;
      float ratio = expf(dg) / (rs + EPS);
      acc += -logf(fmaxf(ratio, EPS));
    }
  }
  if (lane == 0) atomicAdd(loss, acc);
}

__global__ void finalize_kernel(const float* __restrict__ loss,
                                float* __restrict__ out) {
  out[(size_t)STU_N * KNOW] = loss[0] * (1.0f / (float)BATCH);
}

extern "C" void kernel_launch(void* const* d_in, const int* in_sizes, int n_in,
                              void* d_out, int out_size, void* d_ws,
                              size_t ws_size, hipStream_t stream) {
  const float* stu_emb = (const float*)d_in[0];
  const float* exer_emb = (const float*)d_in[1];
  const float* W_ue = (const float*)d_in[2];
  const float* W_ue_per = (const float*)d_in[3];
  const float* W_deep = (const float*)d_in[4];
  const int* src_e = (const int*)d_in[5];
  const int* dst_e = (const int*)d_in[6];
  const int* src_p = (const int*)d_in[7];
  const int* dst_p = (const int*)d_in[8];
  const int* stu_id = (const int*)d_in[9];
  float* out = (float*)d_out;

  // ---- workspace layout ----
  char* wsb = (char*)d_ws;
  // zeroed region first
  int* cnt_e = (int*)wsb;               // 50,000
  int* cnt_p = cnt_e + STU_N;           // 50,000
  int* cur_e = cnt_p + STU_N;           // 50,000
  int* cur_p = cur_e + STU_N;           // 50,000
  float* S2 = (float*)(cur_p + STU_N);  // 128
  float* loss = S2 + KNOW;              // 1
  unsigned char* flag = (unsigned char*)(loss + 1);  // 50,000 bytes
  size_t zero_bytes = (size_t)(flag + ((STU_N + 3) & ~3) - (unsigned char*)wsb);
  // rest (fully overwritten each call)
  float* X_sum = (float*)(flag + ((STU_N + 3) & ~3));   // 2,560,000
  float* X_per = X_sum + (size_t)EXER_N * KNOW;         // 2,560,000
  float* X_deep = X_per + (size_t)EXER_N * KNOW;        // 2,560,000
  int* off_e = (int*)(X_deep + (size_t)EXER_N * KNOW);  // 50,001
  int* off_p = off_e + STU_N + 1;                       // 50,001
  int* csr_e = off_p + STU_N + 1;                       // 1,000,000
  int* csr_p = csr_e + NE;                              // 950,000
  float* n1 = (float*)(csr_p + NEP);                    // 1,048,576
  float* n2 = n1 + (size_t)BATCH * KNOW;                // 1,048,576
  float* diag = n2 + (size_t)BATCH * KNOW;              // 8,192
  int* tsum = (int*)(diag + BATCH);                     // 2*NTILES

  hipMemsetAsync(d_ws, 0, zero_bytes, stream);

  set_flags<<<(BATCH + 255) / 256, 256, 0, stream>>>(stu_id, flag);

  {
    dim3 grid(EXER_N / TBM, 3);
    transform_kernel<<<grid, 256, 0, stream>>>(exer_emb, W_ue, W_ue_per,
                                               W_deep, X_sum, X_per, X_deep);
  }

  count_part<<<NXCD * BGRP, 256, 0, stream>>>(dst_e, dst_p, flag, cnt_e,
                                              cnt_p);

  {
    dim3 grid(NTILES, 2);
    tile_sum_kernel<<<grid, 256, 0, stream>>>(cnt_e, cnt_p, tsum);
    scan_tiles_kernel<<<2, 256, 0, stream>>>(tsum);
    tile_scan_kernel<<<grid, 256, 0, stream>>>(cnt_e, cnt_p, tsum, off_e,
                                               off_p);
  }

  fill_part<<<NXCD * BGRP, 256, 0, stream>>>(src_e, dst_e, src_p, dst_p, flag,
                                             off_e, off_p, cur_e, cur_p, csr_e,
                                             csr_p);

  stu2_gather<<<STU_N, 128, 0, stream>>>(stu_emb, X_sum, csr_e, off_e, out);

  batch_kernel<<<BATCH, 128, 0, stream>>>(stu_emb, out, X_per, X_deep, csr_p,
                                          off_p, csr_e, off_e, stu_id, n1, n2,
                                          diag);

  s2_reduce<<<64, 128, 0, stream>>>(n2, S2);

  loss2<<<L2BLKS, 256, 0, stream>>>(n1, diag, S2, loss);

  finalize_kernel<<<1, 1, 0, stream>>>(loss, out);
}

// Round 8
// 389.773 us; speedup vs baseline: 10.1841x; 1.0217x over previous
//
#include <hip/hip_runtime.h>
#include <math.h>

#define KNOW 128
#define STU_N 50000
#define EXER_N 20000
#define BATCH 8192
#define NE 1000000
#define NEP 950000
#define SOFT_INV 5.0f   // 1/0.2
#define EPS 1e-8f

#define NXCD 8
#define STU_PER_XCD (STU_N / NXCD)  // 6250
#define NCHUNK ((NE + NEP + 255) / 256)
#define BGRP 952  // block-groups per XCD for edge kernels

#define NTILES ((STU_N + 255) / 256)  // 196

typedef unsigned short u16;
typedef unsigned int u32;

__device__ __forceinline__ u16 f2bf(float f) {
  union { float f; u32 u; } v;
  v.f = f;
  u32 r = (v.u + 0x7FFFu + ((v.u >> 16) & 1u)) >> 16;
  return (u16)r;
}
__device__ __forceinline__ float bflo(u32 u) {
  union { u32 u; float f; } v;
  v.u = u << 16;
  return v.f;
}
__device__ __forceinline__ float bfhi(u32 u) {
  union { u32 u; float f; } v;
  v.u = u & 0xFFFF0000u;
  return v.f;
}
__device__ __forceinline__ float bfu(u16 h) {
  union { u32 u; float f; } v;
  v.u = ((u32)h) << 16;
  return v.f;
}

// ---------------- flag sampled students ----------------
__global__ void set_flags(const int* __restrict__ stu_id,
                          unsigned char* __restrict__ flag) {
  int i = blockIdx.x * blockDim.x + threadIdx.x;
  if (i < BATCH) flag[stu_id[i]] = 1;
}

// ---------------- pack edge arrays to u16 ----------------
__global__ __launch_bounds__(256) void pack_kernel(
    const int* __restrict__ dst_e, const int* __restrict__ src_e,
    const int* __restrict__ dst_p, const int* __restrict__ src_p,
    u16* __restrict__ d16e, u16* __restrict__ s16e, u16* __restrict__ d16p,
    u16* __restrict__ s16p) {
  int t = blockIdx.x * blockDim.x + threadIdx.x;
  if (t < NE) {
    d16e[t] = (u16)dst_e[t];
    s16e[t] = (u16)src_e[t];
  } else if (t < NE + NEP) {
    int e = t - NE;
    d16p[e] = (u16)dst_p[e];
    s16p[e] = (u16)src_p[e];
  }
}

// ---------------- CSR count, XCD-partitioned by dst range -------------------
__global__ __launch_bounds__(256) void count_part(
    const u16* __restrict__ d16e, const u16* __restrict__ d16p,
    const unsigned char* __restrict__ flag, int* __restrict__ cnt_e,
    int* __restrict__ cnt_p) {
  int xcd = blockIdx.x & 7;
  int lo = xcd * STU_PER_XCD, hi = lo + STU_PER_XCD;
  for (int c = blockIdx.x >> 3; c < NCHUNK; c += BGRP) {
    int t = (c << 8) + threadIdx.x;
    if (t < NE) {
      int d = d16e[t];
      if (d >= lo && d < hi) atomicAdd(&cnt_e[d], 1);
    } else if (t < NE + NEP) {
      int d = d16p[t - NE];
      if (d >= lo && d < hi && flag[d]) atomicAdd(&cnt_p[d], 1);
    }
  }
}

// ---------------- hierarchical scan, phase A: tile sums ---------------------
__global__ __launch_bounds__(256) void tile_sum_kernel(
    const int* __restrict__ cnt_e, const int* __restrict__ cnt_p,
    int* __restrict__ tsum) {
  __shared__ int red[256];
  const int* cnt = (blockIdx.y == 0) ? cnt_e : cnt_p;
  int i = blockIdx.x * 256 + threadIdx.x;
  red[threadIdx.x] = (i < STU_N) ? cnt[i] : 0;
  __syncthreads();
  for (int s = 128; s > 0; s >>= 1) {
    if (threadIdx.x < s) red[threadIdx.x] += red[threadIdx.x + s];
    __syncthreads();
  }
  if (threadIdx.x == 0) tsum[blockIdx.y * NTILES + blockIdx.x] = red[0];
}

// ---------------- phase B: exclusive-scan the tile sums (in place) ----------
__global__ __launch_bounds__(256) void scan_tiles_kernel(int* __restrict__ tsum) {
  __shared__ int sh[256];
  int* ts = tsum + blockIdx.x * NTILES;
  int t = threadIdx.x;
  int v = (t < NTILES) ? ts[t] : 0;
  sh[t] = v;
  __syncthreads();
  for (int d = 1; d < 256; d <<= 1) {
    int u = (t >= d) ? sh[t - d] : 0;
    __syncthreads();
    sh[t] += u;
    __syncthreads();
  }
  if (t < NTILES) ts[t] = sh[t] - v;  // exclusive
}

// ---------------- phase C: per-tile scan + offset, write off ----------------
__global__ __launch_bounds__(256) void tile_scan_kernel(
    const int* __restrict__ cnt_e, const int* __restrict__ cnt_p,
    const int* __restrict__ tsum, int* __restrict__ off_e,
    int* __restrict__ off_p) {
  __shared__ int sh[256];
  const int* cnt = (blockIdx.y == 0) ? cnt_e : cnt_p;
  int* off = (blockIdx.y == 0) ? off_e : off_p;
  int tile_off = tsum[blockIdx.y * NTILES + blockIdx.x];
  int t = threadIdx.x;
  int i = blockIdx.x * 256 + t;
  int v = (i < STU_N) ? cnt[i] : 0;
  sh[t] = v;
  __syncthreads();
  for (int d = 1; d < 256; d <<= 1) {
    int u = (t >= d) ? sh[t - d] : 0;
    __syncthreads();
    sh[t] += u;
    __syncthreads();
  }
  if (i < STU_N) off[i] = tile_off + sh[t] - v;           // exclusive
  if (i == STU_N - 1) off[STU_N] = tile_off + sh[t];      // total
}

// ---------------- CSR fill, XCD-partitioned by dst range --------------------
__global__ __launch_bounds__(256) void fill_part(
    const u16* __restrict__ s16e, const u16* __restrict__ d16e,
    const u16* __restrict__ s16p, const u16* __restrict__ d16p,
    const unsigned char* __restrict__ flag, const int* __restrict__ off_e,
    const int* __restrict__ off_p, int* __restrict__ cur_e,
    int* __restrict__ cur_p, u16* __restrict__ csr_e,
    u16* __restrict__ csr_p) {
  int xcd = blockIdx.x & 7;
  int lo = xcd * STU_PER_XCD, hi = lo + STU_PER_XCD;
  for (int c = blockIdx.x >> 3; c < NCHUNK; c += BGRP) {
    int t = (c << 8) + threadIdx.x;
    if (t < NE) {
      int d = d16e[t];
      if (d >= lo && d < hi) {
        int p = atomicAdd(&cur_e[d], 1);
        csr_e[off_e[d] + p] = s16e[t];
      }
    } else if (t < NE + NEP) {
      int e = t - NE;
      int d = d16p[e];
      if (d >= lo && d < hi && flag[d]) {
        int p = atomicAdd(&cur_p[d], 1);
        csr_p[off_p[d] + p] = s16p[e];
      }
    }
  }
}

// ------- X_sum/X_per/X_deep (bf16) = exer @ {W_ue+W_deep, W_per, W_deep} ----
#define TBM 32
__global__ __launch_bounds__(256) void transform_kernel(
    const float* __restrict__ exer, const float* __restrict__ W_ue,
    const float* __restrict__ W_per, const float* __restrict__ W_deep,
    u16* __restrict__ X_sum, u16* __restrict__ X_per,
    u16* __restrict__ X_deep) {
  __shared__ float w[KNOW * KNOW];  // 64 KB
  __shared__ float a[TBM * KNOW];   // 16 KB
  int t = threadIdx.x;
  int which = blockIdx.y;
  u16* outp = (which == 0) ? X_sum : (which == 1) ? X_per : X_deep;

  if (which == 0) {
#pragma unroll
    for (int i = t * 4; i < KNOW * KNOW; i += 1024) {
      float4 wa = *(const float4*)(W_ue + i);
      float4 wd = *(const float4*)(W_deep + i);
      float4 o = {wa.x + wd.x, wa.y + wd.y, wa.z + wd.z, wa.w + wd.w};
      *(float4*)(w + i) = o;
    }
  } else {
    const float* Ws = (which == 1) ? W_per : W_deep;
#pragma unroll
    for (int i = t * 4; i < KNOW * KNOW; i += 1024)
      *(float4*)(w + i) = *(const float4*)(Ws + i);
  }
  int r0 = blockIdx.x * TBM;
#pragma unroll
  for (int i = t * 4; i < TBM * KNOW; i += 1024)
    *(float4*)(a + i) = *(const float4*)(exer + (size_t)r0 * KNOW + i);
  __syncthreads();

  int cg = (t & 31) * 4;
  int rg = (t >> 5) * 4;
  float acc[4][4] = {};
  for (int k = 0; k < KNOW; k += 4) {
    float4 wv0 = *(const float4*)(w + (k + 0) * KNOW + cg);
    float4 wv1 = *(const float4*)(w + (k + 1) * KNOW + cg);
    float4 wv2 = *(const float4*)(w + (k + 2) * KNOW + cg);
    float4 wv3 = *(const float4*)(w + (k + 3) * KNOW + cg);
#pragma unroll
    for (int r = 0; r < 4; ++r) {
      float4 av = *(const float4*)(a + (rg + r) * KNOW + k);
      acc[r][0] += av.x * wv0.x + av.y * wv1.x + av.z * wv2.x + av.w * wv3.x;
      acc[r][1] += av.x * wv0.y + av.y * wv1.y + av.z * wv2.y + av.w * wv3.y;
      acc[r][2] += av.x * wv0.z + av.y * wv1.z + av.z * wv2.z + av.w * wv3.z;
      acc[r][3] += av.x * wv0.w + av.y * wv1.w + av.z * wv2.w + av.w * wv3.w;
    }
  }
#pragma unroll
  for (int r = 0; r < 4; ++r) {
    ushort4 o = {f2bf(acc[r][0]), f2bf(acc[r][1]), f2bf(acc[r][2]),
                 f2bf(acc[r][3])};
    *(ushort4*)(outp + (size_t)(r0 + rg + r) * KNOW + cg) = o;
  }
}

// ------- stu2 = stu_emb + mean(X_sum bf16 rows over CSR_e) ------------------
// 8 edge-groups x 16 lanes; each lane loads uint4 = 8 bf16 of a 256B row.
__global__ __launch_bounds__(128) void stu2_gather(
    const float* __restrict__ stu_emb, const u16* __restrict__ X_sum,
    const u16* __restrict__ csr, const int* __restrict__ off,
    float* __restrict__ out) {
  __shared__ float red[128];
  int s = blockIdx.x;
  int t = threadIdx.x;
  int c = t & 15;  // 16B chunk within row
  int g = t >> 4;  // edge group 0..7
  int b = off[s], e = off[s + 1];
  float acc[8] = {};
  for (int i = b + g; i < e; i += 8) {
    const uint4 q = *(const uint4*)(X_sum + (size_t)csr[i] * KNOW + c * 8);
    acc[0] += bflo(q.x);
    acc[1] += bfhi(q.x);
    acc[2] += bflo(q.y);
    acc[3] += bfhi(q.y);
    acc[4] += bflo(q.z);
    acc[5] += bfhi(q.z);
    acc[6] += bflo(q.w);
    acc[7] += bfhi(q.w);
  }
  // reduce groups within each wave: lanes (g*16+c); after two shfl_downs,
  // lanes 0..15 of wave0 hold groups 0-3 sum, wave1 lanes 0..15 groups 4-7.
#pragma unroll
  for (int j = 0; j < 8; ++j) {
    float v = acc[j];
    v += __shfl_down(v, 16);
    v += __shfl_down(v, 32);
    acc[j] = v;
  }
  int lane = t & 63;
  if (t >= 64 && lane < 16) {
#pragma unroll
    for (int j = 0; j < 8; ++j) red[lane * 8 + j] = acc[j];
  }
  __syncthreads();
  if (t < 16) {
    float inv = 1.0f / fmaxf((float)(e - b), 1.0f);
    float4 se0 = *(const float4*)(stu_emb + (size_t)s * KNOW + t * 8);
    float4 se1 = *(const float4*)(stu_emb + (size_t)s * KNOW + t * 8 + 4);
    float r0 = acc[0] + red[t * 8 + 0];
    float r1 = acc[1] + red[t * 8 + 1];
    float r2 = acc[2] + red[t * 8 + 2];
    float r3 = acc[3] + red[t * 8 + 3];
    float r4 = acc[4] + red[t * 8 + 4];
    float r5 = acc[5] + red[t * 8 + 5];
    float r6 = acc[6] + red[t * 8 + 6];
    float r7 = acc[7] + red[t * 8 + 7];
    float4 o0 = {se0.x + r0 * inv, se0.y + r1 * inv, se0.z + r2 * inv,
                 se0.w + r3 * inv};
    float4 o1 = {se1.x + r4 * inv, se1.y + r5 * inv, se1.z + r6 * inv,
                 se1.w + r7 * inv};
    *(float4*)(out + (size_t)s * KNOW + t * 8) = o0;
    *(float4*)(out + (size_t)s * KNOW + t * 8 + 4) = o1;
  }
}

// ---- batch: bf16 gathers, normalize, write n1/n2, diag = n1·n2 -------------
__global__ __launch_bounds__(128) void batch_kernel(
    const float* __restrict__ stu_emb, const float* __restrict__ stu2,
    const u16* __restrict__ X_per, const u16* __restrict__ X_deep,
    const u16* __restrict__ csr_p, const int* __restrict__ off_p,
    const u16* __restrict__ csr_e, const int* __restrict__ off_e,
    const int* __restrict__ stu_id, float* __restrict__ n1,
    float* __restrict__ n2, float* __restrict__ diag) {
  __shared__ float red[128];
  int i = blockIdx.x;
  int k = threadIdx.x;
  int sid = stu_id[i];

  int b = off_p[sid], e = off_p[sid + 1];
  float accp = 0.0f;
  int j = b;
  for (; j + 4 <= e; j += 4) {
    int s0 = csr_p[j], s1 = csr_p[j + 1], s2 = csr_p[j + 2], s3 = csr_p[j + 3];
    accp += bfu(X_per[(size_t)s0 * KNOW + k]);
    accp += bfu(X_per[(size_t)s1 * KNOW + k]);
    accp += bfu(X_per[(size_t)s2 * KNOW + k]);
    accp += bfu(X_per[(size_t)s3 * KNOW + k]);
  }
  for (; j < e; ++j) accp += bfu(X_per[(size_t)csr_p[j] * KNOW + k]);
  accp /= fmaxf((float)(e - b), 1.0f);

  int b2i = off_e[sid], e2i = off_e[sid + 1];
  float accd = 0.0f;
  j = b2i;
  for (; j + 4 <= e2i; j += 4) {
    int s0 = csr_e[j], s1 = csr_e[j + 1], s2 = csr_e[j + 2], s3 = csr_e[j + 3];
    accd += bfu(X_deep[(size_t)s0 * KNOW + k]);
    accd += bfu(X_deep[(size_t)s1 * KNOW + k]);
    accd += bfu(X_deep[(size_t)s2 * KNOW + k]);
    accd += bfu(X_deep[(size_t)s3 * KNOW + k]);
  }
  for (; j < e2i; ++j) accd += bfu(X_deep[(size_t)csr_e[j] * KNOW + k]);
  accd /= fmaxf((float)(e2i - b2i), 1.0f);

  float b1 = stu2[(size_t)sid * KNOW + k];
  float b2 = stu_emb[(size_t)sid * KNOW + k] + accp + accd;

  red[k] = b1 * b1;
  __syncthreads();
  for (int s = 64; s > 0; s >>= 1) {
    if (k < s) red[k] += red[k + s];
    __syncthreads();
  }
  float norm1 = sqrtf(red[0]);
  __syncthreads();
  red[k] = b2 * b2;
  __syncthreads();
  for (int s = 64; s > 0; s >>= 1) {
    if (k < s) red[k] += red[k + s];
    __syncthreads();
  }
  float norm2 = sqrtf(red[0]);

  float v1 = b1 / norm1;
  float v2 = b2 / norm2;
  n1[(size_t)i * KNOW + k] = v1;
  n2[(size_t)i * KNOW + k] = v2;

  __syncthreads();
  red[k] = v1 * v2;
  __syncthreads();
  for (int s = 64; s > 0; s >>= 1) {
    if (k < s) red[k] += red[k + s];
    __syncthreads();
  }
  if (k == 0) diag[i] = red[0];
}

// ---------------- S2[k] = sum_i n2[i][k] (low-contention) -------------------
__global__ __launch_bounds__(128) void s2_reduce(const float* __restrict__ n2,
                                                 float* __restrict__ S2) {
  int k = threadIdx.x;
  int r0 = blockIdx.x * (BATCH / 64);
  float acc = 0.0f;
  for (int r = 0; r < BATCH / 64; ++r) acc += n2[(size_t)(r0 + r) * KNOW + k];
  atomicAdd(&S2[k], acc);
}

// ------ loss2: rowsum_i = n1_i·S2 via wave per row; 1 atomic per wave -------
#define L2BLKS 64
__global__ __launch_bounds__(256) void loss2(const float* __restrict__ n1,
                                             const float* __restrict__ diag,
                                             const float* __restrict__ S2,
                                             float* __restrict__ loss) {
  __shared__ float s2s[KNOW];
  int t = threadIdx.x;
  if (t < KNOW) s2s[t] = S2[t];
  __syncthreads();
  int wave = t >> 6, lane = t & 63;
  const int rows_per_wave = BATCH / (L2BLKS * 4);  // 32
  int r0 = (blockIdx.x * 4 + wave) * rows_per_wave;
  float acc = 0.0f;
  for (int r = r0; r < r0 + rows_per_wave; ++r) {
    float v = n1[(size_t)r * KNOW + lane] * s2s[lane] +
              n1[(size_t)r * KNOW + 64 + lane] * s2s[64 + lane];
#pragma unroll
    for (int off = 32; off > 0; off >>= 1) v += __shfl_down(v, off);
    if (lane == 0) {
      float rs = v * SOFT_INV;
      float dg = diag[r] * SOFT_INV;
      float ratio = expf(dg) / (rs + EPS);
      acc += -logf(fmaxf(ratio, EPS));
    }
  }
  if (lane == 0) atomicAdd(loss, acc);
}

__global__ void finalize_kernel(const float* __restrict__ loss,
                                float* __restrict__ out) {
  out[(size_t)STU_N * KNOW] = loss[0] * (1.0f / (float)BATCH);
}

extern "C" void kernel_launch(void* const* d_in, const int* in_sizes, int n_in,
                              void* d_out, int out_size, void* d_ws,
                              size_t ws_size, hipStream_t stream) {
  const float* stu_emb = (const float*)d_in[0];
  const float* exer_emb = (const float*)d_in[1];
  const float* W_ue = (const float*)d_in[2];
  const float* W_ue_per = (const float*)d_in[3];
  const float* W_deep = (const float*)d_in[4];
  const int* src_e = (const int*)d_in[5];
  const int* dst_e = (const int*)d_in[6];
  const int* src_p = (const int*)d_in[7];
  const int* dst_p = (const int*)d_in[8];
  const int* stu_id = (const int*)d_in[9];
  float* out = (float*)d_out;

  // ---- workspace layout ----
  char* wsb = (char*)d_ws;
  // zeroed region first
  int* cnt_e = (int*)wsb;               // 50,000
  int* cnt_p = cnt_e + STU_N;           // 50,000
  int* cur_e = cnt_p + STU_N;           // 50,000
  int* cur_p = cur_e + STU_N;           // 50,000
  float* S2 = (float*)(cur_p + STU_N);  // 128
  float* loss = S2 + KNOW;              // 1
  unsigned char* flag = (unsigned char*)(loss + 1);  // 50,000 bytes
  size_t zero_bytes = (size_t)(flag + ((STU_N + 3) & ~3) - (unsigned char*)wsb);
  // rest (fully overwritten each call)
  u16* X_sum = (u16*)(flag + ((STU_N + 3) & ~3));       // 2,560,000 u16
  u16* X_per = X_sum + (size_t)EXER_N * KNOW;           // 2,560,000 u16
  u16* X_deep = X_per + (size_t)EXER_N * KNOW;          // 2,560,000 u16
  int* off_e = (int*)(X_deep + (size_t)EXER_N * KNOW);  // 50,001
  int* off_p = off_e + STU_N + 1;                       // 50,001
  u16* d16e = (u16*)(off_p + STU_N + 1);                // NE
  u16* s16e = d16e + NE;                                // NE
  u16* d16p = s16e + NE;                                // NEP
  u16* s16p = d16p + NEP;                               // NEP
  u16* csr_e = s16p + NEP;                              // NE
  u16* csr_p = csr_e + NE;                              // NEP (+pad)
  float* n1 = (float*)(((size_t)(csr_p + NEP) + 15) & ~(size_t)15);  // BATCH*K
  float* n2 = n1 + (size_t)BATCH * KNOW;                // BATCH*K
  float* diag = n2 + (size_t)BATCH * KNOW;              // BATCH
  int* tsum = (int*)(diag + BATCH);                     // 2*NTILES

  hipMemsetAsync(d_ws, 0, zero_bytes, stream);

  set_flags<<<(BATCH + 255) / 256, 256, 0, stream>>>(stu_id, flag);

  pack_kernel<<<(NE + NEP + 255) / 256, 256, 0, stream>>>(
      dst_e, src_e, dst_p, src_p, d16e, s16e, d16p, s16p);

  {
    dim3 grid(EXER_N / TBM, 3);
    transform_kernel<<<grid, 256, 0, stream>>>(exer_emb, W_ue, W_ue_per,
                                               W_deep, X_sum, X_per, X_deep);
  }

  count_part<<<NXCD * BGRP, 256, 0, stream>>>(d16e, d16p, flag, cnt_e, cnt_p);

  {
    dim3 grid(NTILES, 2);
    tile_sum_kernel<<<grid, 256, 0, stream>>>(cnt_e, cnt_p, tsum);
    scan_tiles_kernel<<<2, 256, 0, stream>>>(tsum);
    tile_scan_kernel<<<grid, 256, 0, stream>>>(cnt_e, cnt_p, tsum, off_e,
                                               off_p);
  }

  fill_part<<<NXCD * BGRP, 256, 0, stream>>>(s16e, d16e, s16p, d16p, flag,
                                             off_e, off_p, cur_e, cur_p, csr_e,
                                             csr_p);

  stu2_gather<<<STU_N, 128, 0, stream>>>(stu_emb, X_sum, csr_e, off_e, out);

  batch_kernel<<<BATCH, 128, 0, stream>>>(stu_emb, out, X_per, X_deep, csr_p,
                                          off_p, csr_e, off_e, stu_id, n1, n2,
                                          diag);

  s2_reduce<<<64, 128, 0, stream>>>(n2, S2);

  loss2<<<L2BLKS, 256, 0, stream>>>(n1, diag, S2, loss);

  finalize_kernel<<<1, 1, 0, stream>>>(loss, out);
}